// Round 6
// baseline (422.059 us; speedup 1.0000x reference)
//
#include <hip/hip_runtime.h>
#include <math.h>

// Problem constants
#define BATCH 4
#define SEQ   2048
#define HDIM  128
#define NHEAD 8
#define MROWS (BATCH*SEQ)    // 8192
#define QKVN  (3*NHEAD*HDIM) // 3072
#define YN    (NHEAD*HDIM)   // 1024

#define CS 0.12751744f   // (1/sqrt(128)) * log2(e)

using bfrag = __attribute__((ext_vector_type(8))) short;  // 8 bf16 (4 VGPRs)
using f32x4 = __attribute__((ext_vector_type(4))) float;
using s16x4 = __attribute__((ext_vector_type(4))) short;

__device__ __forceinline__ f32x4 mfma16(bfrag a, bfrag b, f32x4 c) {
    return __builtin_amdgcn_mfma_f32_16x16x32_bf16(a, b, c, 0, 0, 0);
}
__device__ __forceinline__ short f2bf(float f) {
    union { float f; unsigned u; } v; v.f = f;
    unsigned r = v.u + 0x7FFFu + ((v.u >> 16) & 1u);  // RNE
    return (short)(r >> 16);
}
__device__ __forceinline__ f32x4 z4() { f32x4 z; z[0]=0.f; z[1]=0.f; z[2]=0.f; z[3]=0.f; return z; }

// ---------------------------------------------------------------------------
// Converters
// ---------------------------------------------------------------------------
__global__ __launch_bounds__(256) void conv_x(const float* __restrict__ x, short* __restrict__ XB) {
    int i = (blockIdx.x * 256 + threadIdx.x) * 4;
    float4 v = *(const float4*)(x + i);
    s16x4 o; o[0] = f2bf(v.x); o[1] = f2bf(v.y); o[2] = f2bf(v.z); o[3] = f2bf(v.w);
    *(s16x4*)(XB + i) = o;
}
__global__ __launch_bounds__(256) void conv_qkvT(const float* __restrict__ q, short* __restrict__ qT) {
    int t = blockIdx.x * 256 + threadIdx.x;         // 3072*128
    int n = t >> 7, k = t & 127;
    qT[t] = f2bf(q[(size_t)k * QKVN + n]);          // qT[n][k] = qkv[k][n]
}
__global__ __launch_bounds__(256) void conv_projT(const float* __restrict__ p, short* __restrict__ pT) {
    int t = blockIdx.x * 256 + threadIdx.x;         // 128*1024
    int h = t >> 10, r = t & 1023;
    pT[t] = f2bf(p[(size_t)r * HDIM + h]);          // pT[h][r] = proj[r][h]
}

// ---------------------------------------------------------------------------
// GEMM1: computes x @ qkv and scatters Q/K/V into per-head layouts:
//   Qh/Kh/Vh[(b*8+n)*2048 + s2][h]   (bf16, contiguous per head; 8.4M elems each)
// Output col jj (within part) of global row r=b*2048+s maps to:
//   n = s>>8 ; s2 = (s&255)*8 + (jj>>7) ; h = jj&127
// Block tile 128x128 (4 waves, 64x64 each). blockIdx.y encodes part & c8.
// ---------------------------------------------------------------------------
__global__ __launch_bounds__(256) void gemm_qkv(
    const short* __restrict__ XB, const short* __restrict__ qkvT,
    short* __restrict__ Qh, short* __restrict__ Kh, short* __restrict__ Vh)
{
    const int t = threadIdx.x, lane = t & 63, w = t >> 6;
    const int lr = lane & 15, lg = lane >> 4;
    const int m0 = blockIdx.x * 128 + (w >> 1) * 64;
    const int n0 = blockIdx.y * 128 + (w & 1) * 64;

    f32x4 acc[4][4];
    #pragma unroll
    for (int i = 0; i < 4; ++i)
        #pragma unroll
        for (int j = 0; j < 4; ++j) acc[i][j] = z4();

    #pragma unroll
    for (int c = 0; c < 4; ++c) {
        bfrag a[4], bb[4];
        #pragma unroll
        for (int rt = 0; rt < 4; ++rt)
            a[rt] = *(const bfrag*)(XB + (size_t)(m0 + rt * 16 + lr) * 128 + c * 32 + lg * 8);
        #pragma unroll
        for (int nt = 0; nt < 4; ++nt)
            bb[nt] = *(const bfrag*)(qkvT + (size_t)(n0 + nt * 16 + lr) * 128 + c * 32 + lg * 8);
        #pragma unroll
        for (int rt = 0; rt < 4; ++rt)
            #pragma unroll
            for (int nt = 0; nt < 4; ++nt)
                acc[rt][nt] = mfma16(a[rt], bb[nt], acc[rt][nt]);
    }

    const int part = blockIdx.y >> 3, c8 = blockIdx.y & 7;
    short* dst = (part == 0) ? Qh : ((part == 1) ? Kh : Vh);
    #pragma unroll
    for (int rt = 0; rt < 4; ++rt)
        #pragma unroll
        for (int j = 0; j < 4; ++j) {
            int r = m0 + rt * 16 + lg * 4 + j;
            int b = r >> 11, sl = r & 2047;
            int n = sl >> 8, s2 = (sl & 255) * 8 + c8;
            size_t rowbase = ((size_t)((b * 8 + n) * 2048 + s2)) * 128;
            #pragma unroll
            for (int nt = 0; nt < 4; ++nt) {
                int h = (w & 1) * 64 + nt * 16 + lr;
                dst[rowbase + h] = f2bf(acc[rt][nt][j]);
            }
        }
}

// ---------------------------------------------------------------------------
// Transpose V per head: Vh[bn][s2][d] -> Vt[bn][d][s2]. 64x64 LDS tiles,
// coalesced on both sides.
// ---------------------------------------------------------------------------
__global__ __launch_bounds__(256) void transp_v(
    const short* __restrict__ Vh, short* __restrict__ Vt)
{
    __shared__ short Ls[64][72];
    const int bn = blockIdx.z, s20 = blockIdx.x * 64, d0 = blockIdx.y * 64;
    const int t = threadIdx.x;
    const short* src = Vh + ((size_t)bn * SEQ + s20) * 128 + d0;
    {
        int r = t >> 2, ch = (t & 3) * 16;
        *(int4*)&Ls[r][ch]     = *(const int4*)(src + (size_t)r * 128 + ch);
        *(int4*)&Ls[r][ch + 8] = *(const int4*)(src + (size_t)r * 128 + ch + 8);
    }
    __syncthreads();
    {
        int dr = t >> 2, ch = (t & 3) * 16;
        short tmp[16];
        #pragma unroll
        for (int i = 0; i < 16; ++i) tmp[i] = Ls[ch + i][dr];
        short* dp = Vt + ((size_t)bn * HDIM + d0 + dr) * SEQ + s20 + ch;
        *(int4*)dp       = *(int4*)&tmp[0];
        *(int4*)(dp + 8) = *(int4*)&tmp[8];
    }
}

// ---------------------------------------------------------------------------
// Flash attention, 1 wave per block (64 thr), 16 q-rows per block, KVBLK=64.
// 4096 blocks = 32 heads x 128 q-tiles; work-descending dispatch (p = 127-pi)
// so long tiles start first and short tiles backfill. Head->XCD affinity:
// bn low 3 bits = blockIdx&7, so each XCD's L2 caches its 4 heads' K/V (4 MB).
// K/V fragments read straight from global (L1/L2). Only LDS: tiny per-block
// Ps buffer for the P C-layout -> A-layout shuffle; wave-fenced, no barriers.
// ---------------------------------------------------------------------------
__global__ __launch_bounds__(64, 6) void attn3(
    const short* __restrict__ Qh, const short* __restrict__ Kh,
    const short* __restrict__ Vt, short* __restrict__ Y)
{
    __shared__ short Ps[16][72];

    const int lane = threadIdx.x & 63;
    const int lr = lane & 15, lg = lane >> 4;

    const int i  = blockIdx.x;                        // 0..4095
    const int bn = (i & 7) | (((i >> 3) & 3) << 3);   // head id; bn%8 == i%8
    const int p  = 127 - (i >> 5);                    // 16-row tile, descending work
    const int b  = bn >> 3, n = bn & 7;
    const int q0 = p * 16;

    const short* Qb = Qh + (size_t)bn * SEQ * HDIM;
    const short* Kb = Kh + (size_t)bn * SEQ * HDIM;
    const short* Vb = Vt + (size_t)bn * HDIM * SEQ;

    bfrag ones;
    #pragma unroll
    for (int k = 0; k < 8; ++k) ones[k] = (short)0x3F80;   // bf16 1.0

    bfrag qf[4];
    #pragma unroll
    for (int c = 0; c < 4; ++c)
        qf[c] = *(const bfrag*)(Qb + (size_t)(q0 + lr) * 128 + c * 32 + lg * 8);

    float mcs[4], l[4];
    f32x4 o[8];
    #pragma unroll
    for (int j = 0; j < 4; ++j) { mcs[j] = -1.0e30f; l[j] = 0.f; }
    #pragma unroll
    for (int dt = 0; dt < 8; ++dt) o[dt] = z4();

    const int nst = (q0 >> 6) + 1;    // kv-steps: covers [0, q0+16) causally
    for (int s = 0; s < nst; ++s) {
        const int k0 = s * 64;

        // ---- QK^T : S[16 rows][64 cols]
        f32x4 sA[4];
        #pragma unroll
        for (int kt = 0; kt < 4; ++kt) sA[kt] = z4();
        #pragma unroll
        for (int kt = 0; kt < 4; ++kt) {
            const short* kp = Kb + (size_t)(k0 + kt * 16 + lr) * 128 + lg * 8;
            #pragma unroll
            for (int c = 0; c < 4; ++c) {
                bfrag kb = *(const bfrag*)(kp + c * 32);
                sA[kt] = mfma16(qf[c], kb, sA[kt]);
            }
        }
        // causal mask (only the final step can straddle the diagonal)
        if (s == nst - 1) {
            #pragma unroll
            for (int kt = 0; kt < 4; ++kt)
                #pragma unroll
                for (int j = 0; j < 4; ++j)
                    if (k0 + kt * 16 + lr > q0 + lg * 4 + j)
                        sA[kt][j] = -3.0e38f;
        }

        // ---- row max (4 cols in-thread, then 16-lane lr reduce)
        float pm[4];
        bool need = false;
        #pragma unroll
        for (int j = 0; j < 4; ++j) {
            float mx = fmaxf(fmaxf(sA[0][j], sA[1][j]), fmaxf(sA[2][j], sA[3][j]));
            mx = fmaxf(mx, __shfl_xor(mx, 1));
            mx = fmaxf(mx, __shfl_xor(mx, 2));
            mx = fmaxf(mx, __shfl_xor(mx, 4));
            mx = fmaxf(mx, __shfl_xor(mx, 8));
            pm[j] = mx * CS;
            need = need || (pm[j] > mcs[j] + 8.0f);    // T13 defer-rescale
        }
        if (__any(need ? 1 : 0)) {
            #pragma unroll
            for (int j = 0; j < 4; ++j) {
                float nm = fmaxf(mcs[j], pm[j]);
                float al = exp2f(mcs[j] - nm);
                mcs[j] = nm;
                l[j] *= al;
                #pragma unroll
                for (int dt = 0; dt < 8; ++dt) o[dt][j] *= al;
            }
        }

        // ---- P = exp2(S*CS - mcs), staged (C-layout write)
        #pragma unroll
        for (int j = 0; j < 4; ++j) {
            #pragma unroll
            for (int kt = 0; kt < 4; ++kt)
                Ps[lg * 4 + j][kt * 16 + lr] = f2bf(exp2f(sA[kt][j] * CS - mcs[j]));
        }
        asm volatile("s_waitcnt lgkmcnt(0)" ::: "memory");

        // ---- P A-frags; l via P*ones MFMA; PV from global Vt
        bfrag pa0 = *(const bfrag*)&Ps[lr][lg * 8];
        bfrag pa1 = *(const bfrag*)&Ps[lr][32 + lg * 8];
        f32x4 ls = mfma16(pa0, ones, mfma16(pa1, ones, z4()));
        #pragma unroll
        for (int j = 0; j < 4; ++j) l[j] += ls[j];

        #pragma unroll
        for (int dt = 0; dt < 8; ++dt) {
            const short* vp = Vb + (size_t)(dt * 16 + lr) * SEQ + k0 + lg * 8;
            bfrag vb0 = *(const bfrag*)vp;
            bfrag vb1 = *(const bfrag*)(vp + 32);
            o[dt] = mfma16(pa0, vb0, o[dt]);
            o[dt] = mfma16(pa1, vb1, o[dt]);
        }
        asm volatile("s_waitcnt lgkmcnt(0)" ::: "memory");  // pa reads done before next Ps write
    }

    // ---- epilogue: normalize, scatter bf16 into Y[8192][1024]
    #pragma unroll
    for (int j = 0; j < 4; ++j) {
        float inv = 1.0f / l[j];
        int s2 = q0 + lg * 4 + j;
        size_t yrow = (size_t)b * SEQ + n * 256 + (s2 >> 3);
        short* yp = Y + yrow * YN + (s2 & 7) * 128 + lr;
        #pragma unroll
        for (int dt = 0; dt < 8; ++dt)
            yp[dt * 16] = f2bf(o[dt][j] * inv);
    }
}

// ---------------------------------------------------------------------------
// GEMM2: out[8192][128] (f32) = Yb[8192][1024](bf16) @ proj, B as projT[h][k].
// Block = 16 rows x 128 cols; 2 waves, each 16x64; grid 512.
// ---------------------------------------------------------------------------
__global__ __launch_bounds__(128) void gemm_out(
    const short* __restrict__ Yb, const short* __restrict__ projT, float* __restrict__ out)
{
    const int t = threadIdx.x, lane = t & 63, w = t >> 6;   // w in 0..1
    const int lr = lane & 15, lg = lane >> 4;
    const int m0 = blockIdx.x * 16;
    const int n0 = w * 64;

    f32x4 acc[4];
    #pragma unroll
    for (int j = 0; j < 4; ++j) acc[j] = z4();

    for (int c = 0; c < 32; ++c) {
        bfrag a = *(const bfrag*)(Yb + (size_t)(m0 + lr) * YN + c * 32 + lg * 8);
        #pragma unroll
        for (int nt = 0; nt < 4; ++nt) {
            bfrag bb = *(const bfrag*)(projT + (size_t)(n0 + nt * 16 + lr) * YN + c * 32 + lg * 8);
            acc[nt] = mfma16(a, bb, acc[nt]);
        }
    }
    #pragma unroll
    for (int nt = 0; nt < 4; ++nt)
        #pragma unroll
        for (int j = 0; j < 4; ++j)
            out[(size_t)(m0 + lg * 4 + j) * HDIM + n0 + nt * 16 + lr] = acc[nt][j];
}

// ---------------------------------------------------------------------------
extern "C" void kernel_launch(void* const* d_in, const int* in_sizes, int n_in,
                              void* d_out, int out_size, void* d_ws, size_t ws_size,
                              hipStream_t stream)
{
    const float* x    = (const float*)d_in[0];  // [4,2048,128]
    const float* qkv  = (const float*)d_in[1];  // [128,3072]
    const float* proj = (const float*)d_in[2];  // [1024,128]
    float* out = (float*)d_out;                 // [8192,128]

    // Per-head buffers are [32 heads][2048 rows][128] elements each (16 MB bf16).
    const size_t HEADSZ = (size_t)32 * SEQ * HDIM;        // 8,388,608 elements

    short* XB    = (short*)d_ws;                          // 2 MB
    short* qkvT  = XB    + (size_t)MROWS * HDIM;
    short* projT = qkvT  + (size_t)QKVN * HDIM;
    short* Qh    = projT + (size_t)HDIM * YN;             // 16 MB
    short* Kh    = Qh    + HEADSZ;                        // 16 MB
    short* Vh    = Kh    + HEADSZ;                        // 16 MB
    short* Vtb   = Vh    + HEADSZ;                        // 16 MB
    short* Yb    = Vtb   + HEADSZ;                        // 16 MB  (~85 MB total)

    conv_x    <<<MROWS * HDIM / 1024, 256, 0, stream>>>(x, XB);
    conv_qkvT <<<QKVN * HDIM / 256,  256, 0, stream>>>(qkv, qkvT);
    conv_projT<<<HDIM * YN / 256,    256, 0, stream>>>(proj, projT);

    gemm_qkv<<<dim3(MROWS / 128, QKVN / 128), 256, 0, stream>>>(XB, qkvT, Qh, Kh, Vh);
    transp_v<<<dim3(SEQ / 64, HDIM / 64, 32), 256, 0, stream>>>(Vh, Vtb);
    attn3   <<<4096, 64, 0, stream>>>(Qh, Kh, Vtb, Yb);
    gemm_out<<<MROWS / 16, 128, 0, stream>>>(Yb, projT, out);
}

// Round 7
// 337.329 us; speedup vs baseline: 1.2512x; 1.2512x over previous
//
#include <hip/hip_runtime.h>
#include <math.h>

// Problem constants
#define BATCH 4
#define SEQ   2048
#define HDIM  128
#define NHEAD 8
#define MROWS (BATCH*SEQ)    // 8192
#define QKVN  (3*NHEAD*HDIM) // 3072
#define YN    (NHEAD*HDIM)   // 1024

#define CS 0.12751744f   // (1/sqrt(128)) * log2(e)

using bfrag = __attribute__((ext_vector_type(8))) short;  // 8 bf16 (4 VGPRs)
using f32x4 = __attribute__((ext_vector_type(4))) float;
using s16x4 = __attribute__((ext_vector_type(4))) short;

__device__ __forceinline__ f32x4 mfma16(bfrag a, bfrag b, f32x4 c) {
    return __builtin_amdgcn_mfma_f32_16x16x32_bf16(a, b, c, 0, 0, 0);
}
__device__ __forceinline__ short f2bf(float f) {
    union { float f; unsigned u; } v; v.f = f;
    unsigned r = v.u + 0x7FFFu + ((v.u >> 16) & 1u);  // RNE
    return (short)(r >> 16);
}
__device__ __forceinline__ f32x4 z4() { f32x4 z; z[0]=0.f; z[1]=0.f; z[2]=0.f; z[3]=0.f; return z; }

// ---------------------------------------------------------------------------
// Converters
// ---------------------------------------------------------------------------
__global__ __launch_bounds__(256) void conv_x(const float* __restrict__ x, short* __restrict__ XB) {
    int i = (blockIdx.x * 256 + threadIdx.x) * 4;
    float4 v = *(const float4*)(x + i);
    s16x4 o; o[0] = f2bf(v.x); o[1] = f2bf(v.y); o[2] = f2bf(v.z); o[3] = f2bf(v.w);
    *(s16x4*)(XB + i) = o;
}
__global__ __launch_bounds__(256) void conv_qkvT(const float* __restrict__ q, short* __restrict__ qT) {
    int t = blockIdx.x * 256 + threadIdx.x;         // 3072*128
    int n = t >> 7, k = t & 127;
    qT[t] = f2bf(q[(size_t)k * QKVN + n]);          // qT[n][k] = qkv[k][n]
}
__global__ __launch_bounds__(256) void conv_projT(const float* __restrict__ p, short* __restrict__ pT) {
    int t = blockIdx.x * 256 + threadIdx.x;         // 128*1024
    int h = t >> 10, r = t & 1023;
    pT[t] = f2bf(p[(size_t)r * HDIM + h]);          // pT[h][r] = proj[r][h]
}

// ---------------------------------------------------------------------------
// GEMM1: computes x @ qkv and scatters Q/K/V into per-head layouts:
//   Qh/Kh/Vh[(b*8+n)*2048 + s2][h]   (bf16, contiguous per head; 8.4M elems each)
// Output col jj (within part) of global row r=b*2048+s maps to:
//   n = s>>8 ; s2 = (s&255)*8 + (jj>>7) ; h = jj&127
// Block tile 128x128 (4 waves, 64x64 each). blockIdx.y encodes part & c8.
// ---------------------------------------------------------------------------
__global__ __launch_bounds__(256) void gemm_qkv(
    const short* __restrict__ XB, const short* __restrict__ qkvT,
    short* __restrict__ Qh, short* __restrict__ Kh, short* __restrict__ Vh)
{
    const int t = threadIdx.x, lane = t & 63, w = t >> 6;
    const int lr = lane & 15, lg = lane >> 4;
    const int m0 = blockIdx.x * 128 + (w >> 1) * 64;
    const int n0 = blockIdx.y * 128 + (w & 1) * 64;

    f32x4 acc[4][4];
    #pragma unroll
    for (int i = 0; i < 4; ++i)
        #pragma unroll
        for (int j = 0; j < 4; ++j) acc[i][j] = z4();

    #pragma unroll
    for (int c = 0; c < 4; ++c) {
        bfrag a[4], bb[4];
        #pragma unroll
        for (int rt = 0; rt < 4; ++rt)
            a[rt] = *(const bfrag*)(XB + (size_t)(m0 + rt * 16 + lr) * 128 + c * 32 + lg * 8);
        #pragma unroll
        for (int nt = 0; nt < 4; ++nt)
            bb[nt] = *(const bfrag*)(qkvT + (size_t)(n0 + nt * 16 + lr) * 128 + c * 32 + lg * 8);
        #pragma unroll
        for (int rt = 0; rt < 4; ++rt)
            #pragma unroll
            for (int nt = 0; nt < 4; ++nt)
                acc[rt][nt] = mfma16(a[rt], bb[nt], acc[rt][nt]);
    }

    const int part = blockIdx.y >> 3, c8 = blockIdx.y & 7;
    short* dst = (part == 0) ? Qh : ((part == 1) ? Kh : Vh);
    #pragma unroll
    for (int rt = 0; rt < 4; ++rt)
        #pragma unroll
        for (int j = 0; j < 4; ++j) {
            int r = m0 + rt * 16 + lg * 4 + j;
            int b = r >> 11, sl = r & 2047;
            int n = sl >> 8, s2 = (sl & 255) * 8 + c8;
            size_t rowbase = ((size_t)((b * 8 + n) * 2048 + s2)) * 128;
            #pragma unroll
            for (int nt = 0; nt < 4; ++nt) {
                int h = (w & 1) * 64 + nt * 16 + lr;
                dst[rowbase + h] = f2bf(acc[rt][nt][j]);
            }
        }
}

// ---------------------------------------------------------------------------
// Transpose V per head: Vh[bn][s2][d] -> Vt[bn][d][s2]. 64x64 LDS tiles,
// coalesced on both sides.
// ---------------------------------------------------------------------------
__global__ __launch_bounds__(256) void transp_v(
    const short* __restrict__ Vh, short* __restrict__ Vt)
{
    __shared__ short Ls[64][72];
    const int bn = blockIdx.z, s20 = blockIdx.x * 64, d0 = blockIdx.y * 64;
    const int t = threadIdx.x;
    const short* src = Vh + ((size_t)bn * SEQ + s20) * 128 + d0;
    {
        int r = t >> 2, ch = (t & 3) * 16;
        *(int4*)&Ls[r][ch]     = *(const int4*)(src + (size_t)r * 128 + ch);
        *(int4*)&Ls[r][ch + 8] = *(const int4*)(src + (size_t)r * 128 + ch + 8);
    }
    __syncthreads();
    {
        int dr = t >> 2, ch = (t & 3) * 16;
        short tmp[16];
        #pragma unroll
        for (int i = 0; i < 16; ++i) tmp[i] = Ls[ch + i][dr];
        short* dp = Vt + ((size_t)bn * HDIM + d0 + dr) * SEQ + s20 + ch;
        *(int4*)dp       = *(int4*)&tmp[0];
        *(int4*)(dp + 8) = *(int4*)&tmp[8];
    }
}

// ---------------------------------------------------------------------------
// Flash attention: 1024 blocks x 4 waves. Block g handles head bn = g&31
// (bn%8 == g%8 -> XCD affinity) and ONE 64-row q-tile p = 31 - (g>>5)
// (work-descending dispatch: longest tiles first, short ones backfill).
// Wave w owns rows q0 = p*64 + w*16; all 4 waves stream the SAME K/V tiles
// (L1 reuse). KVBLK=64. K/V fragments straight from global (no barriers);
// only LDS: per-wave Ps for the P C-layout -> A-layout shuffle, wave-fenced.
// NO forced occupancy bound (round-6 spill lesson: VGPR cap -> scratch).
// ---------------------------------------------------------------------------
__global__ __launch_bounds__(256) void attn4(
    const short* __restrict__ Qh, const short* __restrict__ Kh,
    const short* __restrict__ Vt, short* __restrict__ Y)
{
    __shared__ short Ps[4][16][72];

    const int t = threadIdx.x, lane = t & 63, w = t >> 6;
    const int lr = lane & 15, lg = lane >> 4;

    const int g  = blockIdx.x;        // 0..1023
    const int bn = g & 31;            // head id; bn%8 == g%8 (XCD affinity)
    const int p  = 31 - (g >> 5);     // 64-row q-tile, descending work
    const int b  = bn >> 3, n = bn & 7;
    const int q0 = p * 64 + w * 16;   // this wave's first q row

    const short* Qb = Qh + (size_t)bn * SEQ * HDIM;
    const short* Kb = Kh + (size_t)bn * SEQ * HDIM;
    const short* Vb = Vt + (size_t)bn * HDIM * SEQ;

    bfrag ones;
    #pragma unroll
    for (int k = 0; k < 8; ++k) ones[k] = (short)0x3F80;   // bf16 1.0

    bfrag qf[4];
    #pragma unroll
    for (int c = 0; c < 4; ++c)
        qf[c] = *(const bfrag*)(Qb + (size_t)(q0 + lr) * 128 + c * 32 + lg * 8);

    float mcs[4], l[4];
    f32x4 o[8];
    #pragma unroll
    for (int j = 0; j < 4; ++j) { mcs[j] = -1.0e30f; l[j] = 0.f; }
    #pragma unroll
    for (int dt = 0; dt < 8; ++dt) o[dt] = z4();

    for (int s = 0; s <= p; ++s) {
        const int k0 = s * 64;

        // ---- QK^T : S[16 rows][64 cols]
        f32x4 sA[4];
        #pragma unroll
        for (int kt = 0; kt < 4; ++kt) sA[kt] = z4();
        #pragma unroll
        for (int kt = 0; kt < 4; ++kt) {
            const short* kp = Kb + (size_t)(k0 + kt * 16 + lr) * 128 + lg * 8;
            #pragma unroll
            for (int c = 0; c < 4; ++c) {
                bfrag kb = *(const bfrag*)(kp + c * 32);
                sA[kt] = mfma16(qf[c], kb, sA[kt]);
            }
        }
        // causal mask (only the diagonal step s==p can mask)
        if (s == p) {
            #pragma unroll
            for (int kt = 0; kt < 4; ++kt)
                #pragma unroll
                for (int j = 0; j < 4; ++j)
                    if (k0 + kt * 16 + lr > q0 + lg * 4 + j)
                        sA[kt][j] = -3.0e38f;
        }

        // ---- row max (4 cols in-thread, then 16-lane lr reduce)
        float pm[4];
        bool need = false;
        #pragma unroll
        for (int j = 0; j < 4; ++j) {
            float mx = fmaxf(fmaxf(sA[0][j], sA[1][j]), fmaxf(sA[2][j], sA[3][j]));
            mx = fmaxf(mx, __shfl_xor(mx, 1));
            mx = fmaxf(mx, __shfl_xor(mx, 2));
            mx = fmaxf(mx, __shfl_xor(mx, 4));
            mx = fmaxf(mx, __shfl_xor(mx, 8));
            pm[j] = mx * CS;
            need = need || (pm[j] > mcs[j] + 8.0f);    // T13 defer-rescale
        }
        if (__any(need ? 1 : 0)) {
            #pragma unroll
            for (int j = 0; j < 4; ++j) {
                float nm = fmaxf(mcs[j], pm[j]);
                float al = exp2f(mcs[j] - nm);
                mcs[j] = nm;
                l[j] *= al;
                #pragma unroll
                for (int dt = 0; dt < 8; ++dt) o[dt][j] *= al;
            }
        }

        // ---- P = exp2(S*CS - mcs), staged per-wave (C-layout write)
        #pragma unroll
        for (int j = 0; j < 4; ++j) {
            #pragma unroll
            for (int kt = 0; kt < 4; ++kt)
                Ps[w][lg * 4 + j][kt * 16 + lr] = f2bf(exp2f(sA[kt][j] * CS - mcs[j]));
        }
        asm volatile("s_waitcnt lgkmcnt(0)" ::: "memory");

        // ---- P A-frags; l via P*ones MFMA; PV from global Vt
        bfrag pa0 = *(const bfrag*)&Ps[w][lr][lg * 8];
        bfrag pa1 = *(const bfrag*)&Ps[w][lr][32 + lg * 8];
        f32x4 ls = mfma16(pa0, ones, mfma16(pa1, ones, z4()));
        #pragma unroll
        for (int j = 0; j < 4; ++j) l[j] += ls[j];

        #pragma unroll
        for (int dt = 0; dt < 8; ++dt) {
            const short* vp = Vb + (size_t)(dt * 16 + lr) * SEQ + k0 + lg * 8;
            bfrag vb0 = *(const bfrag*)vp;
            bfrag vb1 = *(const bfrag*)(vp + 32);
            o[dt] = mfma16(pa0, vb0, o[dt]);
            o[dt] = mfma16(pa1, vb1, o[dt]);
        }
        asm volatile("s_waitcnt lgkmcnt(0)" ::: "memory");  // pa reads done before next Ps write
    }

    // ---- epilogue: normalize, scatter bf16 into Y[8192][1024]
    #pragma unroll
    for (int j = 0; j < 4; ++j) {
        float inv = 1.0f / l[j];
        int s2 = q0 + lg * 4 + j;
        size_t yrow = (size_t)b * SEQ + n * 256 + (s2 >> 3);
        short* yp = Y + yrow * YN + (s2 & 7) * 128 + lr;
        #pragma unroll
        for (int dt = 0; dt < 8; ++dt)
            yp[dt * 16] = f2bf(o[dt][j] * inv);
    }
}

// ---------------------------------------------------------------------------
// GEMM2: out[8192][128] (f32) = Yb[8192][1024](bf16) @ proj, B as projT[h][k].
// Block = 16 rows x 128 cols; 2 waves, each 16x64; grid 512.
// ---------------------------------------------------------------------------
__global__ __launch_bounds__(128) void gemm_out(
    const short* __restrict__ Yb, const short* __restrict__ projT, float* __restrict__ out)
{
    const int t = threadIdx.x, lane = t & 63, w = t >> 6;   // w in 0..1
    const int lr = lane & 15, lg = lane >> 4;
    const int m0 = blockIdx.x * 16;
    const int n0 = w * 64;

    f32x4 acc[4];
    #pragma unroll
    for (int j = 0; j < 4; ++j) acc[j] = z4();

    for (int c = 0; c < 32; ++c) {
        bfrag a = *(const bfrag*)(Yb + (size_t)(m0 + lr) * YN + c * 32 + lg * 8);
        #pragma unroll
        for (int nt = 0; nt < 4; ++nt) {
            bfrag bb = *(const bfrag*)(projT + (size_t)(n0 + nt * 16 + lr) * YN + c * 32 + lg * 8);
            acc[nt] = mfma16(a, bb, acc[nt]);
        }
    }
    #pragma unroll
    for (int nt = 0; nt < 4; ++nt)
        #pragma unroll
        for (int j = 0; j < 4; ++j)
            out[(size_t)(m0 + lg * 4 + j) * HDIM + n0 + nt * 16 + lr] = acc[nt][j];
}

// ---------------------------------------------------------------------------
extern "C" void kernel_launch(void* const* d_in, const int* in_sizes, int n_in,
                              void* d_out, int out_size, void* d_ws, size_t ws_size,
                              hipStream_t stream)
{
    const float* x    = (const float*)d_in[0];  // [4,2048,128]
    const float* qkv  = (const float*)d_in[1];  // [128,3072]
    const float* proj = (const float*)d_in[2];  // [1024,128]
    float* out = (float*)d_out;                 // [8192,128]

    // Per-head buffers are [32 heads][2048 rows][128] elements each (16 MB bf16).
    const size_t HEADSZ = (size_t)32 * SEQ * HDIM;        // 8,388,608 elements

    short* XB    = (short*)d_ws;                          // 2 MB
    short* qkvT  = XB    + (size_t)MROWS * HDIM;
    short* projT = qkvT  + (size_t)QKVN * HDIM;
    short* Qh    = projT + (size_t)HDIM * YN;             // 16 MB
    short* Kh    = Qh    + HEADSZ;                        // 16 MB
    short* Vh    = Kh    + HEADSZ;                        // 16 MB
    short* Vtb   = Vh    + HEADSZ;                        // 16 MB
    short* Yb    = Vtb   + HEADSZ;                        // 16 MB  (~85 MB total)

    conv_x    <<<MROWS * HDIM / 1024, 256, 0, stream>>>(x, XB);
    conv_qkvT <<<QKVN * HDIM / 256,  256, 0, stream>>>(qkv, qkvT);
    conv_projT<<<HDIM * YN / 256,    256, 0, stream>>>(proj, projT);

    gemm_qkv<<<dim3(MROWS / 128, QKVN / 128), 256, 0, stream>>>(XB, qkvT, Qh, Kh, Vh);
    transp_v<<<dim3(SEQ / 64, HDIM / 64, 32), 256, 0, stream>>>(Vh, Vtb);
    attn4   <<<1024, 256, 0, stream>>>(Qh, Kh, Vtb, Yb);
    gemm_out<<<MROWS / 16, 128, 0, stream>>>(Yb, projT, out);
}

// Round 8
// 248.589 us; speedup vs baseline: 1.6978x; 1.3570x over previous
//
#include <hip/hip_runtime.h>
#include <math.h>

// Problem constants
#define BATCH 4
#define SEQ   2048
#define HDIM  128
#define NHEAD 8
#define MROWS (BATCH*SEQ)    // 8192
#define QKVN  (3*NHEAD*HDIM) // 3072
#define YN    (NHEAD*HDIM)   // 1024

#define CS 0.12751744f   // (1/sqrt(128)) * log2(e)

using bfrag = __attribute__((ext_vector_type(8))) short;  // 8 bf16 (4 VGPRs)
using f32x4 = __attribute__((ext_vector_type(4))) float;
using s16x4 = __attribute__((ext_vector_type(4))) short;

__device__ __forceinline__ f32x4 mfma16(bfrag a, bfrag b, f32x4 c) {
    return __builtin_amdgcn_mfma_f32_16x16x32_bf16(a, b, c, 0, 0, 0);
}
__device__ __forceinline__ short f2bf(float f) {
    union { float f; unsigned u; } v; v.f = f;
    unsigned r = v.u + 0x7FFFu + ((v.u >> 16) & 1u);  // RNE
    return (short)(r >> 16);
}
__device__ __forceinline__ f32x4 z4() { f32x4 z; z[0]=0.f; z[1]=0.f; z[2]=0.f; z[3]=0.f; return z; }

// ---------------------------------------------------------------------------
// Converters
// ---------------------------------------------------------------------------
__global__ __launch_bounds__(256) void conv_x(const float* __restrict__ x, short* __restrict__ XB) {
    int i = (blockIdx.x * 256 + threadIdx.x) * 4;
    float4 v = *(const float4*)(x + i);
    s16x4 o; o[0] = f2bf(v.x); o[1] = f2bf(v.y); o[2] = f2bf(v.z); o[3] = f2bf(v.w);
    *(s16x4*)(XB + i) = o;
}
__global__ __launch_bounds__(256) void conv_qkvT(const float* __restrict__ q, short* __restrict__ qT) {
    int t = blockIdx.x * 256 + threadIdx.x;         // 3072*128
    int n = t >> 7, k = t & 127;
    qT[t] = f2bf(q[(size_t)k * QKVN + n]);          // qT[n][k] = qkv[k][n]
}
__global__ __launch_bounds__(256) void conv_projT(const float* __restrict__ p, short* __restrict__ pT) {
    int t = blockIdx.x * 256 + threadIdx.x;         // 128*1024
    int h = t >> 10, r = t & 1023;
    pT[t] = f2bf(p[(size_t)r * HDIM + h]);          // pT[h][r] = proj[r][h]
}

// ---------------------------------------------------------------------------
// GEMM1: computes x @ qkv and scatters Q/K/V into per-head layouts:
//   Qh/Kh/Vh[(b*8+n)*2048 + s2][h]   (bf16, contiguous per head)
// ---------------------------------------------------------------------------
__global__ __launch_bounds__(256) void gemm_qkv(
    const short* __restrict__ XB, const short* __restrict__ qkvT,
    short* __restrict__ Qh, short* __restrict__ Kh, short* __restrict__ Vh)
{
    const int t = threadIdx.x, lane = t & 63, w = t >> 6;
    const int lr = lane & 15, lg = lane >> 4;
    const int m0 = blockIdx.x * 128 + (w >> 1) * 64;
    const int n0 = blockIdx.y * 128 + (w & 1) * 64;

    f32x4 acc[4][4];
    #pragma unroll
    for (int i = 0; i < 4; ++i)
        #pragma unroll
        for (int j = 0; j < 4; ++j) acc[i][j] = z4();

    #pragma unroll
    for (int c = 0; c < 4; ++c) {
        bfrag a[4], bb[4];
        #pragma unroll
        for (int rt = 0; rt < 4; ++rt)
            a[rt] = *(const bfrag*)(XB + (size_t)(m0 + rt * 16 + lr) * 128 + c * 32 + lg * 8);
        #pragma unroll
        for (int nt = 0; nt < 4; ++nt)
            bb[nt] = *(const bfrag*)(qkvT + (size_t)(n0 + nt * 16 + lr) * 128 + c * 32 + lg * 8);
        #pragma unroll
        for (int rt = 0; rt < 4; ++rt)
            #pragma unroll
            for (int nt = 0; nt < 4; ++nt)
                acc[rt][nt] = mfma16(a[rt], bb[nt], acc[rt][nt]);
    }

    const int part = blockIdx.y >> 3, c8 = blockIdx.y & 7;
    short* dst = (part == 0) ? Qh : ((part == 1) ? Kh : Vh);
    #pragma unroll
    for (int rt = 0; rt < 4; ++rt)
        #pragma unroll
        for (int j = 0; j < 4; ++j) {
            int r = m0 + rt * 16 + lg * 4 + j;
            int b = r >> 11, sl = r & 2047;
            int n = sl >> 8, s2 = (sl & 255) * 8 + c8;
            size_t rowbase = ((size_t)((b * 8 + n) * 2048 + s2)) * 128;
            #pragma unroll
            for (int nt = 0; nt < 4; ++nt) {
                int h = (w & 1) * 64 + nt * 16 + lr;
                dst[rowbase + h] = f2bf(acc[rt][nt][j]);
            }
        }
}

// ---------------------------------------------------------------------------
// Transpose V per head: Vh[bn][s2][d] -> Vt[bn][d][s2].
// ---------------------------------------------------------------------------
__global__ __launch_bounds__(256) void transp_v(
    const short* __restrict__ Vh, short* __restrict__ Vt)
{
    __shared__ short Ls[64][72];
    const int bn = blockIdx.z, s20 = blockIdx.x * 64, d0 = blockIdx.y * 64;
    const int t = threadIdx.x;
    const short* src = Vh + ((size_t)bn * SEQ + s20) * 128 + d0;
    {
        int r = t >> 2, ch = (t & 3) * 16;
        *(int4*)&Ls[r][ch]     = *(const int4*)(src + (size_t)r * 128 + ch);
        *(int4*)&Ls[r][ch + 8] = *(const int4*)(src + (size_t)r * 128 + ch + 8);
    }
    __syncthreads();
    {
        int dr = t >> 2, ch = (t & 3) * 16;
        short tmp[16];
        #pragma unroll
        for (int i = 0; i < 16; ++i) tmp[i] = Ls[ch + i][dr];
        short* dp = Vt + ((size_t)bn * HDIM + d0 + dr) * SEQ + s20 + ch;
        *(int4*)dp       = *(int4*)&tmp[0];
        *(int4*)(dp + 8) = *(int4*)&tmp[8];
    }
}

// ---------------------------------------------------------------------------
// attn5: LDS-staged, double-buffered flash attention.
// 512 blocks = 32 heads x 16 q-tiles (QBLK=128), work-descending, XCD-affine
// (bn%8 == g%8). 4 waves/block; wave owns 32 q-rows (2 row-tiles of 16).
// KVBLK=64: K tile (64x128) and Vt tile (128x64) reg-staged into LDS once per
// block-step (T14 issue-early/write-late), double-buffered, ONE barrier/step.
// XOR swizzle col16 ^= (row&7) on both write and read -> conflict-free b128.
// P staged per-wave in Ps[16][72] in two row-tile passes (wave-local fences).
// ---------------------------------------------------------------------------
__global__ __launch_bounds__(256) void attn5(
    const short* __restrict__ Qh, const short* __restrict__ Kh,
    const short* __restrict__ Vt, short* __restrict__ Y)
{
    __shared__ __align__(16) short Kls[2][64 * 128];   // 32 KB
    __shared__ __align__(16) short Vls[2][128 * 64];   // 32 KB
    __shared__ short Ps[4][16][72];                    // 9 KB

    const int t = threadIdx.x, lane = t & 63, w = t >> 6;
    const int lr = lane & 15, lg = lane >> 4;

    const int g  = blockIdx.x;        // 0..511
    const int bn = g & 31;            // head id; bn%8 == g%8 (XCD affinity)
    const int tl = 15 - (g >> 5);     // 128-row q-tile, descending work
    const int b  = bn >> 3, n = bn & 7;
    const int q0 = tl * 128 + w * 32; // this wave's first q row

    const short* Qb = Qh + (size_t)bn * SEQ * HDIM;
    const short* Kb = Kh + (size_t)bn * SEQ * HDIM;
    const short* Vb = Vt + (size_t)bn * HDIM * SEQ;

    // staging geometry: each thread owns 64 B of K and 64 B of V per step
    const int krow = t >> 2, kc4 = (t & 3) * 4;   // K: row 0..63, col16 base
    const int vrow = t >> 1, vc4 = (t & 1) * 4;   // V: row 0..127, col16 base
    const short* gkb = Kb + (size_t)krow * HDIM + (t & 3) * 32;
    const short* gvb = Vb + (size_t)vrow * SEQ + (t & 1) * 32;

    bfrag ones;
    #pragma unroll
    for (int k = 0; k < 8; ++k) ones[k] = (short)0x3F80;   // bf16 1.0

    bfrag qf[2][4];
    #pragma unroll
    for (int rt = 0; rt < 2; ++rt)
        #pragma unroll
        for (int c = 0; c < 4; ++c)
            qf[rt][c] = *(const bfrag*)(Qb + (size_t)(q0 + rt * 16 + lr) * 128 + c * 32 + lg * 8);

    float mcs[2][4], l[2][4];
    f32x4 o[2][8];
    #pragma unroll
    for (int rt = 0; rt < 2; ++rt) {
        #pragma unroll
        for (int j = 0; j < 4; ++j) { mcs[rt][j] = -1.0e30f; l[rt][j] = 0.f; }
        #pragma unroll
        for (int dt = 0; dt < 8; ++dt) o[rt][dt] = z4();
    }

    const int smax = 2 * tl + 1;      // steps 0..smax cover kv [0, q-tile end)

    int4 kreg[4], vreg[4];
    // ---- prologue: stage step 0 into buffer 0
    #pragma unroll
    for (int i = 0; i < 4; ++i) kreg[i] = *(const int4*)(gkb + i * 8);
    #pragma unroll
    for (int i = 0; i < 4; ++i) vreg[i] = *(const int4*)(gvb + i * 8);
    #pragma unroll
    for (int i = 0; i < 4; ++i)
        *(int4*)((char*)&Kls[0][0] + krow * 256 + ((kc4 + i) ^ (krow & 7)) * 16) = kreg[i];
    #pragma unroll
    for (int i = 0; i < 4; ++i)
        *(int4*)((char*)&Vls[0][0] + vrow * 128 + ((vc4 + i) ^ (vrow & 7)) * 16) = vreg[i];
    __syncthreads();

    for (int s = 0; s <= smax; ++s) {
        const int cur = s & 1;
        const int k0 = s * 64;

        // ---- T14 issue-early: global loads for step s+1
        if (s < smax) {
            const short* gk = gkb + (size_t)(k0 + 64) * HDIM;
            const short* gv = gvb + (k0 + 64);
            #pragma unroll
            for (int i = 0; i < 4; ++i) kreg[i] = *(const int4*)(gk + i * 8);
            #pragma unroll
            for (int i = 0; i < 4; ++i) vreg[i] = *(const int4*)(gv + i * 8);
        }

        const bool active = (k0 <= q0 + 31);   // wave-uniform; skip fully-masked steps
        if (active) {
            // ---- QK^T: S[2rt x 16 rows][64 cols] from swizzled K LDS
            f32x4 sA[2][4];
            #pragma unroll
            for (int rt = 0; rt < 2; ++rt)
                #pragma unroll
                for (int kt = 0; kt < 4; ++kt) sA[rt][kt] = z4();
            __builtin_amdgcn_s_setprio(1);
            #pragma unroll
            for (int kt = 0; kt < 4; ++kt) {
                const char* kbase = (const char*)&Kls[cur][0] + (kt * 16 + lr) * 256;
                #pragma unroll
                for (int c = 0; c < 4; ++c) {
                    bfrag kb = *(const bfrag*)(kbase + (((c * 4 + lg) ^ (lr & 7)) * 16));
                    sA[0][kt] = mfma16(qf[0][c], kb, sA[0][kt]);
                    sA[1][kt] = mfma16(qf[1][c], kb, sA[1][kt]);
                }
            }
            __builtin_amdgcn_s_setprio(0);

            // ---- causal mask (only near-diagonal steps)
            if (k0 + 63 > q0) {
                #pragma unroll
                for (int rt = 0; rt < 2; ++rt)
                    #pragma unroll
                    for (int kt = 0; kt < 4; ++kt)
                        #pragma unroll
                        for (int j = 0; j < 4; ++j)
                            if (k0 + kt * 16 + lr > q0 + rt * 16 + lg * 4 + j)
                                sA[rt][kt][j] = -3.0e38f;
            }

            // ---- row max + T13 defer-rescale (per row-tile)
            bool need = false;
            float pm[2][4];
            #pragma unroll
            for (int rt = 0; rt < 2; ++rt)
                #pragma unroll
                for (int j = 0; j < 4; ++j) {
                    float mx = fmaxf(fmaxf(sA[rt][0][j], sA[rt][1][j]),
                                     fmaxf(sA[rt][2][j], sA[rt][3][j]));
                    mx = fmaxf(mx, __shfl_xor(mx, 1));
                    mx = fmaxf(mx, __shfl_xor(mx, 2));
                    mx = fmaxf(mx, __shfl_xor(mx, 4));
                    mx = fmaxf(mx, __shfl_xor(mx, 8));
                    pm[rt][j] = mx * CS;
                    need = need || (pm[rt][j] > mcs[rt][j] + 8.0f);
                }
            if (__any(need ? 1 : 0)) {
                #pragma unroll
                for (int rt = 0; rt < 2; ++rt)
                    #pragma unroll
                    for (int j = 0; j < 4; ++j) {
                        float nm = fmaxf(mcs[rt][j], pm[rt][j]);
                        float al = exp2f(mcs[rt][j] - nm);
                        mcs[rt][j] = nm;
                        l[rt][j] *= al;
                        #pragma unroll
                        for (int dt = 0; dt < 8; ++dt) o[rt][dt][j] *= al;
                    }
            }

            // ---- P staged per-wave, two row-tile passes through Ps[16][72]
            bfrag paA[2], paB[2];
            #pragma unroll
            for (int rt = 0; rt < 2; ++rt) {
                #pragma unroll
                for (int j = 0; j < 4; ++j)
                    #pragma unroll
                    for (int kt = 0; kt < 4; ++kt)
                        Ps[w][lg * 4 + j][kt * 16 + lr] =
                            f2bf(exp2f(sA[rt][kt][j] * CS - mcs[rt][j]));
                asm volatile("s_waitcnt lgkmcnt(0)" ::: "memory");
                paA[rt] = *(const bfrag*)&Ps[w][lr][lg * 8];
                paB[rt] = *(const bfrag*)&Ps[w][lr][32 + lg * 8];
                asm volatile("s_waitcnt lgkmcnt(0)" ::: "memory");  // reads done before overwrite
            }

            // ---- l via P*ones MFMA; PV from swizzled Vt LDS
            #pragma unroll
            for (int rt = 0; rt < 2; ++rt) {
                f32x4 ls = mfma16(paA[rt], ones, mfma16(paB[rt], ones, z4()));
                #pragma unroll
                for (int j = 0; j < 4; ++j) l[rt][j] += ls[j];
            }
            __builtin_amdgcn_s_setprio(1);
            #pragma unroll
            for (int dt = 0; dt < 8; ++dt) {
                const char* vbase = (const char*)&Vls[cur][0] + (dt * 16 + lr) * 128;
                bfrag vb0 = *(const bfrag*)(vbase + ((lg ^ (lr & 7)) * 16));
                bfrag vb1 = *(const bfrag*)(vbase + (((4 + lg) ^ (lr & 7)) * 16));
                #pragma unroll
                for (int rt = 0; rt < 2; ++rt) {
                    o[rt][dt] = mfma16(paA[rt], vb0, o[rt][dt]);
                    o[rt][dt] = mfma16(paB[rt], vb1, o[rt][dt]);
                }
            }
            __builtin_amdgcn_s_setprio(0);
        }

        // ---- write-late: stage s+1 into the other buffer
        if (s < smax) {
            const int nb = cur ^ 1;
            #pragma unroll
            for (int i = 0; i < 4; ++i)
                *(int4*)((char*)&Kls[nb][0] + krow * 256 + ((kc4 + i) ^ (krow & 7)) * 16) = kreg[i];
            #pragma unroll
            for (int i = 0; i < 4; ++i)
                *(int4*)((char*)&Vls[nb][0] + vrow * 128 + ((vc4 + i) ^ (vrow & 7)) * 16) = vreg[i];
        }
        __syncthreads();
    }

    // ---- epilogue: normalize, scatter bf16 into Y[8192][1024]
    #pragma unroll
    for (int rt = 0; rt < 2; ++rt)
        #pragma unroll
        for (int j = 0; j < 4; ++j) {
            float inv = 1.0f / l[rt][j];
            int s2 = q0 + rt * 16 + lg * 4 + j;
            size_t yrow = (size_t)b * SEQ + n * 256 + (s2 >> 3);
            short* yp = Y + yrow * YN + (s2 & 7) * 128 + lr;
            #pragma unroll
            for (int dt = 0; dt < 8; ++dt)
                yp[dt * 16] = f2bf(o[rt][dt][j] * inv);
        }
}

// ---------------------------------------------------------------------------
// GEMM2: out[8192][128] (f32) = Yb[8192][1024](bf16) @ proj, B as projT[h][k].
// ---------------------------------------------------------------------------
__global__ __launch_bounds__(128) void gemm_out(
    const short* __restrict__ Yb, const short* __restrict__ projT, float* __restrict__ out)
{
    const int t = threadIdx.x, lane = t & 63, w = t >> 6;   // w in 0..1
    const int lr = lane & 15, lg = lane >> 4;
    const int m0 = blockIdx.x * 16;
    const int n0 = w * 64;

    f32x4 acc[4];
    #pragma unroll
    for (int j = 0; j < 4; ++j) acc[j] = z4();

    for (int c = 0; c < 32; ++c) {
        bfrag a = *(const bfrag*)(Yb + (size_t)(m0 + lr) * YN + c * 32 + lg * 8);
        #pragma unroll
        for (int nt = 0; nt < 4; ++nt) {
            bfrag bb = *(const bfrag*)(projT + (size_t)(n0 + nt * 16 + lr) * YN + c * 32 + lg * 8);
            acc[nt] = mfma16(a, bb, acc[nt]);
        }
    }
    #pragma unroll
    for (int nt = 0; nt < 4; ++nt)
        #pragma unroll
        for (int j = 0; j < 4; ++j)
            out[(size_t)(m0 + lg * 4 + j) * HDIM + n0 + nt * 16 + lr] = acc[nt][j];
}

// ---------------------------------------------------------------------------
extern "C" void kernel_launch(void* const* d_in, const int* in_sizes, int n_in,
                              void* d_out, int out_size, void* d_ws, size_t ws_size,
                              hipStream_t stream)
{
    const float* x    = (const float*)d_in[0];  // [4,2048,128]
    const float* qkv  = (const float*)d_in[1];  // [128,3072]
    const float* proj = (const float*)d_in[2];  // [1024,128]
    float* out = (float*)d_out;                 // [8192,128]

    // Per-head buffers: [32 heads][2048 rows][128] elements each (16 MB bf16).
    const size_t HEADSZ = (size_t)32 * SEQ * HDIM;        // 8,388,608 elements

    short* XB    = (short*)d_ws;                          // 2 MB
    short* qkvT  = XB    + (size_t)MROWS * HDIM;
    short* projT = qkvT  + (size_t)QKVN * HDIM;
    short* Qh    = projT + (size_t)HDIM * YN;             // 16 MB
    short* Kh    = Qh    + HEADSZ;                        // 16 MB
    short* Vh    = Kh    + HEADSZ;                        // 16 MB
    short* Vtb   = Vh    + HEADSZ;                        // 16 MB
    short* Yb    = Vtb   + HEADSZ;                        // 16 MB  (~85 MB total)

    conv_x    <<<MROWS * HDIM / 1024, 256, 0, stream>>>(x, XB);
    conv_qkvT <<<QKVN * HDIM / 256,  256, 0, stream>>>(qkv, qkvT);
    conv_projT<<<HDIM * YN / 256,    256, 0, stream>>>(proj, projT);

    gemm_qkv<<<dim3(MROWS / 128, QKVN / 128), 256, 0, stream>>>(XB, qkvT, Qh, Kh, Vh);
    transp_v<<<dim3(SEQ / 64, HDIM / 64, 32), 256, 0, stream>>>(Vh, Vtb);
    attn5   <<<512, 256, 0, stream>>>(Qh, Kh, Vtb, Yb);
    gemm_out<<<MROWS / 16, 128, 0, stream>>>(Yb, projT, out);
}

// Round 9
// 189.709 us; speedup vs baseline: 2.2248x; 1.3104x over previous
//
#include <hip/hip_runtime.h>
#include <math.h>

// Problem constants
#define BATCH 4
#define SEQ   2048
#define HDIM  128
#define NHEAD 8
#define MROWS (BATCH*SEQ)    // 8192
#define QKVN  (3*NHEAD*HDIM) // 3072
#define YN    (NHEAD*HDIM)   // 1024

#define CS 0.12751744f   // (1/sqrt(128)) * log2(e)

using bfrag = __attribute__((ext_vector_type(8))) short;  // 8 bf16 (4 VGPRs)
using f32x4 = __attribute__((ext_vector_type(4))) float;
using s16x4 = __attribute__((ext_vector_type(4))) short;

__device__ __forceinline__ f32x4 mfma16(bfrag a, bfrag b, f32x4 c) {
    return __builtin_amdgcn_mfma_f32_16x16x32_bf16(a, b, c, 0, 0, 0);
}
__device__ __forceinline__ short f2bf(float f) {
    union { float f; unsigned u; } v; v.f = f;
    unsigned r = v.u + 0x7FFFu + ((v.u >> 16) & 1u);  // RNE
    return (short)(r >> 16);
}
__device__ __forceinline__ f32x4 z4() { f32x4 z; z[0]=0.f; z[1]=0.f; z[2]=0.f; z[3]=0.f; return z; }

// ---------------------------------------------------------------------------
// Converters
// ---------------------------------------------------------------------------
__global__ __launch_bounds__(256) void conv_x(const float* __restrict__ x, short* __restrict__ XB) {
    int i = (blockIdx.x * 256 + threadIdx.x) * 4;
    float4 v = *(const float4*)(x + i);
    s16x4 o; o[0] = f2bf(v.x); o[1] = f2bf(v.y); o[2] = f2bf(v.z); o[3] = f2bf(v.w);
    *(s16x4*)(XB + i) = o;
}
__global__ __launch_bounds__(256) void conv_qkvT(const float* __restrict__ q, short* __restrict__ qT) {
    int t = blockIdx.x * 256 + threadIdx.x;         // 3072*128
    int n = t >> 7, k = t & 127;
    qT[t] = f2bf(q[(size_t)k * QKVN + n]);          // qT[n][k] = qkv[k][n]
}
__global__ __launch_bounds__(256) void conv_projT(const float* __restrict__ p, short* __restrict__ pT) {
    int t = blockIdx.x * 256 + threadIdx.x;         // 128*1024
    int h = t >> 10, r = t & 1023;
    pT[t] = f2bf(p[(size_t)r * HDIM + h]);          // pT[h][r] = proj[r][h]
}

// ---------------------------------------------------------------------------
// GEMM1: computes x @ qkv and scatters Q/K/V into per-head layouts:
//   Qh/Kh/Vh[(b*8+n)*2048 + s2][h]   (bf16, contiguous per head)
// ---------------------------------------------------------------------------
__global__ __launch_bounds__(256) void gemm_qkv(
    const short* __restrict__ XB, const short* __restrict__ qkvT,
    short* __restrict__ Qh, short* __restrict__ Kh, short* __restrict__ Vh)
{
    const int t = threadIdx.x, lane = t & 63, w = t >> 6;
    const int lr = lane & 15, lg = lane >> 4;
    const int m0 = blockIdx.x * 128 + (w >> 1) * 64;
    const int n0 = blockIdx.y * 128 + (w & 1) * 64;

    f32x4 acc[4][4];
    #pragma unroll
    for (int i = 0; i < 4; ++i)
        #pragma unroll
        for (int j = 0; j < 4; ++j) acc[i][j] = z4();

    #pragma unroll
    for (int c = 0; c < 4; ++c) {
        bfrag a[4], bb[4];
        #pragma unroll
        for (int rt = 0; rt < 4; ++rt)
            a[rt] = *(const bfrag*)(XB + (size_t)(m0 + rt * 16 + lr) * 128 + c * 32 + lg * 8);
        #pragma unroll
        for (int nt = 0; nt < 4; ++nt)
            bb[nt] = *(const bfrag*)(qkvT + (size_t)(n0 + nt * 16 + lr) * 128 + c * 32 + lg * 8);
        #pragma unroll
        for (int rt = 0; rt < 4; ++rt)
            #pragma unroll
            for (int nt = 0; nt < 4; ++nt)
                acc[rt][nt] = mfma16(a[rt], bb[nt], acc[rt][nt]);
    }

    const int part = blockIdx.y >> 3, c8 = blockIdx.y & 7;
    short* dst = (part == 0) ? Qh : ((part == 1) ? Kh : Vh);
    #pragma unroll
    for (int rt = 0; rt < 4; ++rt)
        #pragma unroll
        for (int j = 0; j < 4; ++j) {
            int r = m0 + rt * 16 + lg * 4 + j;
            int b = r >> 11, sl = r & 2047;
            int n = sl >> 8, s2 = (sl & 255) * 8 + c8;
            size_t rowbase = ((size_t)((b * 8 + n) * 2048 + s2)) * 128;
            #pragma unroll
            for (int nt = 0; nt < 4; ++nt) {
                int h = (w & 1) * 64 + nt * 16 + lr;
                dst[rowbase + h] = f2bf(acc[rt][nt][j]);
            }
        }
}

// ---------------------------------------------------------------------------
// Transpose V per head: Vh[bn][s2][d] -> Vt[bn][d][s2].
// ---------------------------------------------------------------------------
__global__ __launch_bounds__(256) void transp_v(
    const short* __restrict__ Vh, short* __restrict__ Vt)
{
    __shared__ short Ls[64][72];
    const int bn = blockIdx.z, s20 = blockIdx.x * 64, d0 = blockIdx.y * 64;
    const int t = threadIdx.x;
    const short* src = Vh + ((size_t)bn * SEQ + s20) * 128 + d0;
    {
        int r = t >> 2, ch = (t & 3) * 16;
        *(int4*)&Ls[r][ch]     = *(const int4*)(src + (size_t)r * 128 + ch);
        *(int4*)&Ls[r][ch + 8] = *(const int4*)(src + (size_t)r * 128 + ch + 8);
    }
    __syncthreads();
    {
        int dr = t >> 2, ch = (t & 3) * 16;
        short tmp[16];
        #pragma unroll
        for (int i = 0; i < 16; ++i) tmp[i] = Ls[ch + i][dr];
        short* dp = Vt + ((size_t)bn * HDIM + d0 + dr) * SEQ + s20 + ch;
        *(int4*)dp       = *(int4*)&tmp[0];
        *(int4*)(dp + 8) = *(int4*)&tmp[8];
    }
}

// ---------------------------------------------------------------------------
// attn6: global_load_lds-staged, double-buffered, perfectly balanced.
// 512 blocks = 32 heads x 16 tile-PAIRS (pp, 31-pp) at QBLK=64 -> every block
// runs exactly 33 kv-steps. XCD affinity: bn%8 == g%8. 4 waves x 16 q-rows.
// KVBLK=64. K (64x128) and Vt (128x64) staged via global_load_lds width=16:
// linear LDS dest, XOR-involution pre-swizzled GLOBAL source (chunk^=row&7),
// same XOR on the read side -> conflict-free b128 reads (rule #21).
// One barrier per step; loads for s+1 issue before compute of s.
// No reg-staging => no spill (round-8 lesson: WRITE_SIZE is the tripwire).
// ---------------------------------------------------------------------------
__global__ __launch_bounds__(256) void attn6(
    const short* __restrict__ Qh, const short* __restrict__ Kh,
    const short* __restrict__ Vt, short* __restrict__ Y)
{
    __shared__ __align__(16) short Kls[2][64 * 128];   // 32 KB
    __shared__ __align__(16) short Vls[2][128 * 64];   // 32 KB
    __shared__ short Ps[4][16][72];                    // 9 KB

    const int t = threadIdx.x, lane = t & 63, w = t >> 6;
    const int lr = lane & 15, lg = lane >> 4;

    const int g  = blockIdx.x;        // 0..511
    const int bn = g & 31;            // head id; bn%8 == g%8 (XCD affinity)
    const int pp = g >> 5;            // pair id 0..15 -> tiles (pp, 31-pp)
    const int b  = bn >> 3, n = bn & 7;

    const short* Qb = Qh + (size_t)bn * SEQ * HDIM;
    const short* Kb = Kh + (size_t)bn * SEQ * HDIM;
    const short* Vb = Vt + (size_t)bn * HDIM * SEQ;

    // async staging: per wave 4 K-instrs + 4 V-instrs, 1 KB each.
    // K instr i: rows 4*(4w+i)..+3 ; lane -> row 4q+(lane>>4), chunk lane&15.
    // V instr i: dims 8*(4w+i)..+7 ; lane -> d 8q+(lane>>3), chunk lane&7.
    auto stage = [&](int buf, int k0) {
        #pragma unroll
        for (int i = 0; i < 4; ++i) {
            const int q = w * 4 + i;
            const int rowK = q * 4 + (lane >> 4);
            const short* src = Kb + (size_t)(k0 + rowK) * 128 + (((lane & 15) ^ (rowK & 7)) * 8);
            __builtin_amdgcn_global_load_lds(
                (const __attribute__((address_space(1))) unsigned int*)src,
                (__attribute__((address_space(3))) unsigned int*)&Kls[buf][q * 512 + lane * 8],
                16, 0, 0);
        }
        #pragma unroll
        for (int i = 0; i < 4; ++i) {
            const int q = w * 4 + i;
            const int d = q * 8 + (lane >> 3);
            const short* src = Vb + (size_t)d * SEQ + k0 + (((lane & 7) ^ (d & 7)) * 8);
            __builtin_amdgcn_global_load_lds(
                (const __attribute__((address_space(1))) unsigned int*)src,
                (__attribute__((address_space(3))) unsigned int*)&Vls[buf][q * 512 + lane * 8],
                16, 0, 0);
        }
    };

    bfrag ones;
    #pragma unroll
    for (int k = 0; k < 8; ++k) ones[k] = (short)0x3F80;   // bf16 1.0

    #pragma unroll 1
    for (int phase = 0; phase < 2; ++phase) {
        const int tile = phase ? pp : (31 - pp);    // long tile first
        const int q0 = tile * 64 + w * 16;

        bfrag qf[4];
        #pragma unroll
        for (int c = 0; c < 4; ++c)
            qf[c] = *(const bfrag*)(Qb + (size_t)(q0 + lr) * 128 + c * 32 + lg * 8);

        float mcs[4], l[4];
        f32x4 o[8];
        #pragma unroll
        for (int j = 0; j < 4; ++j) { mcs[j] = -1.0e30f; l[j] = 0.f; }
        #pragma unroll
        for (int dt = 0; dt < 8; ++dt) o[dt] = z4();

        stage(0, 0);
        __syncthreads();   // drains vmcnt -> buffer 0 full

        for (int s = 0; s <= tile; ++s) {
            const int cur = s & 1;
            const int k0 = s * 64;
            if (s < tile) stage(cur ^ 1, k0 + 64);   // fill other buffer during compute

            // ---- QK^T: S[16 rows][64 cols] from swizzled K LDS
            f32x4 sA[4];
            #pragma unroll
            for (int kt = 0; kt < 4; ++kt) sA[kt] = z4();
            const int ktend = (s == tile) ? (w + 1) : 4;  // skip fully-masked sub-tiles
            __builtin_amdgcn_s_setprio(1);
            for (int kt = 0; kt < ktend; ++kt) {
                const char* kbase = (const char*)&Kls[cur][0] + (kt * 16 + lr) * 256;
                #pragma unroll
                for (int c = 0; c < 4; ++c) {
                    bfrag kb = *(const bfrag*)(kbase + (((c * 4 + lg) ^ (lr & 7)) * 16));
                    sA[kt] = mfma16(qf[c], kb, sA[kt]);
                }
            }
            __builtin_amdgcn_s_setprio(0);

            // ---- causal mask (diagonal step only); kt >= ktend rows are 0 -> masked here
            if (s == tile) {
                #pragma unroll
                for (int kt = 0; kt < 4; ++kt)
                    #pragma unroll
                    for (int j = 0; j < 4; ++j)
                        if (kt * 16 + lr > w * 16 + lg * 4 + j)
                            sA[kt][j] = -3.0e38f;
            }

            // ---- row max + T13 defer-rescale
            float pm[4];
            bool need = false;
            #pragma unroll
            for (int j = 0; j < 4; ++j) {
                float mx = fmaxf(fmaxf(sA[0][j], sA[1][j]), fmaxf(sA[2][j], sA[3][j]));
                mx = fmaxf(mx, __shfl_xor(mx, 1));
                mx = fmaxf(mx, __shfl_xor(mx, 2));
                mx = fmaxf(mx, __shfl_xor(mx, 4));
                mx = fmaxf(mx, __shfl_xor(mx, 8));
                pm[j] = mx * CS;
                need = need || (pm[j] > mcs[j] + 8.0f);
            }
            if (__any(need ? 1 : 0)) {
                #pragma unroll
                for (int j = 0; j < 4; ++j) {
                    float nm = fmaxf(mcs[j], pm[j]);
                    float al = exp2f(mcs[j] - nm);
                    mcs[j] = nm;
                    l[j] *= al;
                    #pragma unroll
                    for (int dt = 0; dt < 8; ++dt) o[dt][j] *= al;
                }
            }

            // ---- P = exp2(S*CS - mcs), staged per-wave (wave-local fences)
            #pragma unroll
            for (int j = 0; j < 4; ++j)
                #pragma unroll
                for (int kt = 0; kt < 4; ++kt)
                    Ps[w][lg * 4 + j][kt * 16 + lr] = f2bf(exp2f(sA[kt][j] * CS - mcs[j]));
            asm volatile("s_waitcnt lgkmcnt(0)" ::: "memory");
            bfrag pa0 = *(const bfrag*)&Ps[w][lr][lg * 8];
            bfrag pa1 = *(const bfrag*)&Ps[w][lr][32 + lg * 8];

            // ---- l via P*ones MFMA; PV from swizzled Vt LDS
            f32x4 ls = mfma16(pa0, ones, mfma16(pa1, ones, z4()));
            #pragma unroll
            for (int j = 0; j < 4; ++j) l[j] += ls[j];

            __builtin_amdgcn_s_setprio(1);
            #pragma unroll
            for (int dt = 0; dt < 8; ++dt) {
                const char* vbase = (const char*)&Vls[cur][0] + (dt * 16 + lr) * 128;
                bfrag vb0 = *(const bfrag*)(vbase + ((lg ^ (lr & 7)) * 16));
                bfrag vb1 = *(const bfrag*)(vbase + (((4 + lg) ^ (lr & 7)) * 16));
                o[dt] = mfma16(pa0, vb0, o[dt]);
                o[dt] = mfma16(pa1, vb1, o[dt]);
            }
            __builtin_amdgcn_s_setprio(0);

            __syncthreads();   // drains vmcnt (s+1 loads) + all LDS reads of cur
        }

        // ---- epilogue: normalize, scatter bf16 into Y[8192][1024]
        #pragma unroll
        for (int j = 0; j < 4; ++j) {
            float inv = 1.0f / l[j];
            int s2 = q0 + lg * 4 + j;
            size_t yrow = (size_t)b * SEQ + n * 256 + (s2 >> 3);
            short* yp = Y + yrow * YN + (s2 & 7) * 128 + lr;
            #pragma unroll
            for (int dt = 0; dt < 8; ++dt)
                yp[dt * 16] = f2bf(o[dt][j] * inv);
        }
    }
}

// ---------------------------------------------------------------------------
// GEMM2: out[8192][128] (f32) = Yb[8192][1024](bf16) @ proj, B as projT[h][k].
// ---------------------------------------------------------------------------
__global__ __launch_bounds__(128) void gemm_out(
    const short* __restrict__ Yb, const short* __restrict__ projT, float* __restrict__ out)
{
    const int t = threadIdx.x, lane = t & 63, w = t >> 6;   // w in 0..1
    const int lr = lane & 15, lg = lane >> 4;
    const int m0 = blockIdx.x * 16;
    const int n0 = w * 64;

    f32x4 acc[4];
    #pragma unroll
    for (int j = 0; j < 4; ++j) acc[j] = z4();

    for (int c = 0; c < 32; ++c) {
        bfrag a = *(const bfrag*)(Yb + (size_t)(m0 + lr) * YN + c * 32 + lg * 8);
        #pragma unroll
        for (int nt = 0; nt < 4; ++nt) {
            bfrag bb = *(const bfrag*)(projT + (size_t)(n0 + nt * 16 + lr) * YN + c * 32 + lg * 8);
            acc[nt] = mfma16(a, bb, acc[nt]);
        }
    }
    #pragma unroll
    for (int nt = 0; nt < 4; ++nt)
        #pragma unroll
        for (int j = 0; j < 4; ++j)
            out[(size_t)(m0 + lg * 4 + j) * HDIM + n0 + nt * 16 + lr] = acc[nt][j];
}

// ---------------------------------------------------------------------------
extern "C" void kernel_launch(void* const* d_in, const int* in_sizes, int n_in,
                              void* d_out, int out_size, void* d_ws, size_t ws_size,
                              hipStream_t stream)
{
    const float* x    = (const float*)d_in[0];  // [4,2048,128]
    const float* qkv  = (const float*)d_in[1];  // [128,3072]
    const float* proj = (const float*)d_in[2];  // [1024,128]
    float* out = (float*)d_out;                 // [8192,128]

    // Per-head buffers: [32 heads][2048 rows][128] elements each (16 MB bf16).
    const size_t HEADSZ = (size_t)32 * SEQ * HDIM;        // 8,388,608 elements

    short* XB    = (short*)d_ws;                          // 2 MB
    short* qkvT  = XB    + (size_t)MROWS * HDIM;
    short* projT = qkvT  + (size_t)QKVN * HDIM;
    short* Qh    = projT + (size_t)HDIM * YN;             // 16 MB
    short* Kh    = Qh    + HEADSZ;                        // 16 MB
    short* Vh    = Kh    + HEADSZ;                        // 16 MB
    short* Vtb   = Vh    + HEADSZ;                        // 16 MB
    short* Yb    = Vtb   + HEADSZ;                        // 16 MB  (~85 MB total)

    conv_x    <<<MROWS * HDIM / 1024, 256, 0, stream>>>(x, XB);
    conv_qkvT <<<QKVN * HDIM / 256,  256, 0, stream>>>(qkv, qkvT);
    conv_projT<<<HDIM * YN / 256,    256, 0, stream>>>(proj, projT);

    gemm_qkv<<<dim3(MROWS / 128, QKVN / 128), 256, 0, stream>>>(XB, qkvT, Qh, Kh, Vh);
    transp_v<<<dim3(SEQ / 64, HDIM / 64, 32), 256, 0, stream>>>(Vh, Vtb);
    attn6   <<<512, 256, 0, stream>>>(Qh, Kh, Vtb, Yb);
    gemm_out<<<MROWS / 16, 128, 0, stream>>>(Yb, projT, out);
}

// Round 10
// 186.124 us; speedup vs baseline: 2.2676x; 1.0193x over previous
//
#include <hip/hip_runtime.h>
#include <math.h>

// Problem constants
#define BATCH 4
#define SEQ   2048
#define HDIM  128
#define NHEAD 8
#define MROWS (BATCH*SEQ)    // 8192
#define QKVN  (3*NHEAD*HDIM) // 3072
#define YN    (NHEAD*HDIM)   // 1024

#define CS 0.12751744f   // (1/sqrt(128)) * log2(e)

using bfrag = __attribute__((ext_vector_type(8))) short;  // 8 bf16 (4 VGPRs)
using f32x4 = __attribute__((ext_vector_type(4))) float;
using s16x4 = __attribute__((ext_vector_type(4))) short;

__device__ __forceinline__ f32x4 mfma16(bfrag a, bfrag b, f32x4 c) {
    return __builtin_amdgcn_mfma_f32_16x16x32_bf16(a, b, c, 0, 0, 0);
}
__device__ __forceinline__ short f2bf(float f) {
    union { float f; unsigned u; } v; v.f = f;
    unsigned r = v.u + 0x7FFFu + ((v.u >> 16) & 1u);  // RNE
    return (short)(r >> 16);
}
__device__ __forceinline__ unsigned cvtpk(float lo, float hi) {
    unsigned r;
    asm("v_cvt_pk_bf16_f32 %0, %1, %2" : "=v"(r) : "v"(lo), "v"(hi));
    return r;   // bits[15:0]=bf16(lo), bits[31:16]=bf16(hi)
}
__device__ __forceinline__ f32x4 z4() { f32x4 z; z[0]=0.f; z[1]=0.f; z[2]=0.f; z[3]=0.f; return z; }

// ---------------------------------------------------------------------------
// Converters
// ---------------------------------------------------------------------------
__global__ __launch_bounds__(256) void conv_x(const float* __restrict__ x, short* __restrict__ XB) {
    int i = (blockIdx.x * 256 + threadIdx.x) * 4;
    float4 v = *(const float4*)(x + i);
    s16x4 o; o[0] = f2bf(v.x); o[1] = f2bf(v.y); o[2] = f2bf(v.z); o[3] = f2bf(v.w);
    *(s16x4*)(XB + i) = o;
}
__global__ __launch_bounds__(256) void conv_qkvT(const float* __restrict__ q, short* __restrict__ qT) {
    int t = blockIdx.x * 256 + threadIdx.x;         // 3072*128
    int n = t >> 7, k = t & 127;
    qT[t] = f2bf(q[(size_t)k * QKVN + n]);          // qT[n][k] = qkv[k][n]
}
__global__ __launch_bounds__(256) void conv_projT(const float* __restrict__ p, short* __restrict__ pT) {
    int t = blockIdx.x * 256 + threadIdx.x;         // 128*1024
    int h = t >> 10, r = t & 1023;
    pT[t] = f2bf(p[(size_t)r * HDIM + h]);          // pT[h][r] = proj[r][h]
}

// ---------------------------------------------------------------------------
// GEMM1: computes x @ qkv and scatters Q/K/V into per-head layouts:
//   Qh/Kh/Vh[(b*8+n)*2048 + s2][h]   (bf16, contiguous per head)
// ---------------------------------------------------------------------------
__global__ __launch_bounds__(256) void gemm_qkv(
    const short* __restrict__ XB, const short* __restrict__ qkvT,
    short* __restrict__ Qh, short* __restrict__ Kh, short* __restrict__ Vh)
{
    const int t = threadIdx.x, lane = t & 63, w = t >> 6;
    const int lr = lane & 15, lg = lane >> 4;
    const int m0 = blockIdx.x * 128 + (w >> 1) * 64;
    const int n0 = blockIdx.y * 128 + (w & 1) * 64;

    f32x4 acc[4][4];
    #pragma unroll
    for (int i = 0; i < 4; ++i)
        #pragma unroll
        for (int j = 0; j < 4; ++j) acc[i][j] = z4();

    #pragma unroll
    for (int c = 0; c < 4; ++c) {
        bfrag a[4], bb[4];
        #pragma unroll
        for (int rt = 0; rt < 4; ++rt)
            a[rt] = *(const bfrag*)(XB + (size_t)(m0 + rt * 16 + lr) * 128 + c * 32 + lg * 8);
        #pragma unroll
        for (int nt = 0; nt < 4; ++nt)
            bb[nt] = *(const bfrag*)(qkvT + (size_t)(n0 + nt * 16 + lr) * 128 + c * 32 + lg * 8);
        #pragma unroll
        for (int rt = 0; rt < 4; ++rt)
            #pragma unroll
            for (int nt = 0; nt < 4; ++nt)
                acc[rt][nt] = mfma16(a[rt], bb[nt], acc[rt][nt]);
    }

    const int part = blockIdx.y >> 3, c8 = blockIdx.y & 7;
    short* dst = (part == 0) ? Qh : ((part == 1) ? Kh : Vh);
    #pragma unroll
    for (int rt = 0; rt < 4; ++rt)
        #pragma unroll
        for (int j = 0; j < 4; ++j) {
            int r = m0 + rt * 16 + lg * 4 + j;
            int b = r >> 11, sl = r & 2047;
            int n = sl >> 8, s2 = (sl & 255) * 8 + c8;
            size_t rowbase = ((size_t)((b * 8 + n) * 2048 + s2)) * 128;
            #pragma unroll
            for (int nt = 0; nt < 4; ++nt) {
                int h = (w & 1) * 64 + nt * 16 + lr;
                dst[rowbase + h] = f2bf(acc[rt][nt][j]);
            }
        }
}

// ---------------------------------------------------------------------------
// Transpose V per head: Vh[bn][s2][d] -> Vt[bn][d][s2].
// ---------------------------------------------------------------------------
__global__ __launch_bounds__(256) void transp_v(
    const short* __restrict__ Vh, short* __restrict__ Vt)
{
    __shared__ short Ls[64][72];
    const int bn = blockIdx.z, s20 = blockIdx.x * 64, d0 = blockIdx.y * 64;
    const int t = threadIdx.x;
    const short* src = Vh + ((size_t)bn * SEQ + s20) * 128 + d0;
    {
        int r = t >> 2, ch = (t & 3) * 16;
        *(int4*)&Ls[r][ch]     = *(const int4*)(src + (size_t)r * 128 + ch);
        *(int4*)&Ls[r][ch + 8] = *(const int4*)(src + (size_t)r * 128 + ch + 8);
    }
    __syncthreads();
    {
        int dr = t >> 2, ch = (t & 3) * 16;
        short tmp[16];
        #pragma unroll
        for (int i = 0; i < 16; ++i) tmp[i] = Ls[ch + i][dr];
        short* dp = Vt + ((size_t)bn * HDIM + d0 + dr) * SEQ + s20 + ch;
        *(int4*)dp       = *(int4*)&tmp[0];
        *(int4*)(dp + 8) = *(int4*)&tmp[8];
    }
}

// ---------------------------------------------------------------------------
// attn7: attn6 skeleton (global_load_lds dbuf staging, tile-pairing balance,
// XCD affinity) + SWAPPED QK^T in-register softmax.
// mfma(K,Q) puts S^T[k][q] with q = lane&15 -> each lane owns one full P-row:
//   row-max = in-lane fmax tree + shfl_xor(16,32)   (was 16 shfls)
//   l       = in-lane sum + shfl_xor(16,32)         (drops P*ones MFMAs)
//   mcs/l   = one scalar per lane                   (was [4])
// P -> A-frag transpose: 8 cvt_pk + 4 ds_write_b64 + 2 ds_read_b128 per step
// (was 16 ds_write_b16 + 2 reads + 2 fences), chunk^(lr&7) XOR both sides.
// ---------------------------------------------------------------------------
__global__ __launch_bounds__(256) void attn7(
    const short* __restrict__ Qh, const short* __restrict__ Kh,
    const short* __restrict__ Vt, short* __restrict__ Y)
{
    __shared__ __align__(16) short Kls[2][64 * 128];   // 32 KB
    __shared__ __align__(16) short Vls[2][128 * 64];   // 32 KB
    __shared__ __align__(16) short Ps[4][16][72];      // 9 KB (144 B rows)

    const int t = threadIdx.x, lane = t & 63, w = t >> 6;
    const int lr = lane & 15, lg = lane >> 4;

    const int g  = blockIdx.x;        // 0..511
    const int bn = g & 31;            // head id; bn%8 == g%8 (XCD affinity)
    const int pp = g >> 5;            // pair id 0..15 -> tiles (pp, 31-pp)
    const int b  = bn >> 3, n = bn & 7;

    const short* Qb = Qh + (size_t)bn * SEQ * HDIM;
    const short* Kb = Kh + (size_t)bn * SEQ * HDIM;
    const short* Vb = Vt + (size_t)bn * HDIM * SEQ;

    // async staging (unchanged from attn6): linear LDS dest, pre-swizzled src
    auto stage = [&](int buf, int k0) {
        #pragma unroll
        for (int i = 0; i < 4; ++i) {
            const int q = w * 4 + i;
            const int rowK = q * 4 + (lane >> 4);
            const short* src = Kb + (size_t)(k0 + rowK) * 128 + (((lane & 15) ^ (rowK & 7)) * 8);
            __builtin_amdgcn_global_load_lds(
                (const __attribute__((address_space(1))) unsigned int*)src,
                (__attribute__((address_space(3))) unsigned int*)&Kls[buf][q * 512 + lane * 8],
                16, 0, 0);
        }
        #pragma unroll
        for (int i = 0; i < 4; ++i) {
            const int q = w * 4 + i;
            const int d = q * 8 + (lane >> 3);
            const short* src = Vb + (size_t)d * SEQ + k0 + (((lane & 7) ^ (d & 7)) * 8);
            __builtin_amdgcn_global_load_lds(
                (const __attribute__((address_space(1))) unsigned int*)src,
                (__attribute__((address_space(3))) unsigned int*)&Vls[buf][q * 512 + lane * 8],
                16, 0, 0);
        }
    };

    // per-wave P staging region, row = q-row (lr), 144 B rows
    char* PsW = (char*)&Ps[w][0][0] + lr * 144;
    const int sw = lr & 7;   // XOR involution key for this lane's row

    #pragma unroll 1
    for (int phase = 0; phase < 2; ++phase) {
        const int tile = phase ? pp : (31 - pp);    // long tile first
        const int q0 = tile * 64 + w * 16;

        bfrag qf[4];
        #pragma unroll
        for (int c = 0; c < 4; ++c)
            qf[c] = *(const bfrag*)(Qb + (size_t)(q0 + lr) * 128 + c * 32 + lg * 8);

        float mcs = -1.0e30f, l = 0.f;              // per-lane: q = q0 + lr
        f32x4 o[8];
        #pragma unroll
        for (int dt = 0; dt < 8; ++dt) o[dt] = z4();

        stage(0, 0);
        __syncthreads();   // drains vmcnt -> buffer 0 full

        for (int s = 0; s <= tile; ++s) {
            const int cur = s & 1;
            const int k0 = s * 64;
            if (s < tile) stage(cur ^ 1, k0 + 64);   // fill other buffer during compute

            // ---- swapped QK^T: sA[kt] = S^T[k = kt*16+lg*4+j][q = q0+lr]
            f32x4 sA[4];
            #pragma unroll
            for (int kt = 0; kt < 4; ++kt) sA[kt] = z4();
            const int ktend = (s == tile) ? (w + 1) : 4;  // skip fully-masked sub-tiles
            __builtin_amdgcn_s_setprio(1);
            for (int kt = 0; kt < ktend; ++kt) {
                const char* kbase = (const char*)&Kls[cur][0] + (kt * 16 + lr) * 256;
                #pragma unroll
                for (int c = 0; c < 4; ++c) {
                    bfrag kb = *(const bfrag*)(kbase + (((c * 4 + lg) ^ sw) * 16));
                    sA[kt] = mfma16(kb, qf[c], sA[kt]);   // swapped operands
                }
            }
            __builtin_amdgcn_s_setprio(0);

            // ---- causal mask (diagonal step only): k_local > q_local
            if (s == tile) {
                #pragma unroll
                for (int kt = 0; kt < 4; ++kt)
                    #pragma unroll
                    for (int j = 0; j < 4; ++j)
                        if (kt * 16 + lg * 4 + j > w * 16 + lr)
                            sA[kt][j] = -3.0e38f;
            }

            // ---- row max: in-lane tree + 2 cross-lg shuffles (full k-row)
            float mx = fmaxf(fmaxf(sA[0][0], sA[0][1]), fmaxf(sA[0][2], sA[0][3]));
            #pragma unroll
            for (int kt = 1; kt < 4; ++kt)
                mx = fmaxf(mx, fmaxf(fmaxf(sA[kt][0], sA[kt][1]),
                                     fmaxf(sA[kt][2], sA[kt][3])));
            mx = fmaxf(mx, __shfl_xor(mx, 16));
            mx = fmaxf(mx, __shfl_xor(mx, 32));
            const float pmx = mx * CS;

            // ---- T13 defer-rescale (rare)
            if (__any((pmx > mcs + 8.0f) ? 1 : 0)) {
                float nm = fmaxf(mcs, pmx);
                float al = exp2f(mcs - nm);
                mcs = nm;
                l *= al;
                float alj[4];
                #pragma unroll
                for (int j = 0; j < 4; ++j) alj[j] = __shfl(al, lg * 4 + j);
                #pragma unroll
                for (int dt = 0; dt < 8; ++dt)
                    #pragma unroll
                    for (int j = 0; j < 4; ++j) o[dt][j] *= alj[j];
            }

            // ---- P = exp2(S*CS - mcs) (lane-local row), l-sum, cvt_pk pack
            float p[4][4];
            float ls = 0.f;
            #pragma unroll
            for (int kt = 0; kt < 4; ++kt)
                #pragma unroll
                for (int j = 0; j < 4; ++j) {
                    p[kt][j] = exp2f(sA[kt][j] * CS - mcs);
                    ls += p[kt][j];
                }
            ls += __shfl_xor(ls, 16);
            ls += __shfl_xor(ls, 32);
            l += ls;

            // ---- stage P: 4 ds_write_b64, chunk^(lr&7) swizzle
            #pragma unroll
            for (int kt = 0; kt < 4; ++kt) {
                uint2 wv;
                wv.x = cvtpk(p[kt][0], p[kt][1]);
                wv.y = cvtpk(p[kt][2], p[kt][3]);
                const int ccw = kt * 2 + (lg >> 1);          // 16B chunk of this k-range
                *(uint2*)(PsW + ((ccw ^ sw) * 16) + (lg & 1) * 8) = wv;
            }
            asm volatile("s_waitcnt lgkmcnt(0)" ::: "memory");
            bfrag pa0 = *(const bfrag*)(PsW + ((lg ^ sw) * 16));         // k 0..31 chunk lg
            bfrag pa1 = *(const bfrag*)(PsW + (((4 + lg) ^ sw) * 16));   // k 32..63

            // ---- PV from swizzled Vt LDS
            __builtin_amdgcn_s_setprio(1);
            #pragma unroll
            for (int dt = 0; dt < 8; ++dt) {
                const char* vbase = (const char*)&Vls[cur][0] + (dt * 16 + lr) * 128;
                bfrag vb0 = *(const bfrag*)(vbase + ((lg ^ sw) * 16));
                bfrag vb1 = *(const bfrag*)(vbase + (((4 + lg) ^ sw) * 16));
                o[dt] = mfma16(pa0, vb0, o[dt]);
                o[dt] = mfma16(pa1, vb1, o[dt]);
            }
            __builtin_amdgcn_s_setprio(0);

            __syncthreads();   // drains vmcnt (s+1 loads) + all LDS reads/writes
        }

        // ---- epilogue: l (q=lr layout) -> per-j inverses, scatter bf16 to Y
        float inv[4];
        #pragma unroll
        for (int j = 0; j < 4; ++j) inv[j] = 1.0f / __shfl(l, lg * 4 + j);
        #pragma unroll
        for (int j = 0; j < 4; ++j) {
            int s2 = q0 + lg * 4 + j;
            size_t yrow = (size_t)b * SEQ + n * 256 + (s2 >> 3);
            short* yp = Y + yrow * YN + (s2 & 7) * 128 + lr;
            #pragma unroll
            for (int dt = 0; dt < 8; ++dt)
                yp[dt * 16] = f2bf(o[dt][j] * inv[j]);
        }
    }
}

// ---------------------------------------------------------------------------
// GEMM2: out[8192][128] (f32) = Yb[8192][1024](bf16) @ proj, B as projT[h][k].
// ---------------------------------------------------------------------------
__global__ __launch_bounds__(128) void gemm_out(
    const short* __restrict__ Yb, const short* __restrict__ projT, float* __restrict__ out)
{
    const int t = threadIdx.x, lane = t & 63, w = t >> 6;   // w in 0..1
    const int lr = lane & 15, lg = lane >> 4;
    const int m0 = blockIdx.x * 16;
    const int n0 = w * 64;

    f32x4 acc[4];
    #pragma unroll
    for (int j = 0; j < 4; ++j) acc[j] = z4();

    for (int c = 0; c < 32; ++c) {
        bfrag a = *(const bfrag*)(Yb + (size_t)(m0 + lr) * YN + c * 32 + lg * 8);
        #pragma unroll
        for (int nt = 0; nt < 4; ++nt) {
            bfrag bb = *(const bfrag*)(projT + (size_t)(n0 + nt * 16 + lr) * YN + c * 32 + lg * 8);
            acc[nt] = mfma16(a, bb, acc[nt]);
        }
    }
    #pragma unroll
    for (int nt = 0; nt < 4; ++nt)
        #pragma unroll
        for (int j = 0; j < 4; ++j)
            out[(size_t)(m0 + lg * 4 + j) * HDIM + n0 + nt * 16 + lr] = acc[nt][j];
}

// ---------------------------------------------------------------------------
extern "C" void kernel_launch(void* const* d_in, const int* in_sizes, int n_in,
                              void* d_out, int out_size, void* d_ws, size_t ws_size,
                              hipStream_t stream)
{
    const float* x    = (const float*)d_in[0];  // [4,2048,128]
    const float* qkv  = (const float*)d_in[1];  // [128,3072]
    const float* proj = (const float*)d_in[2];  // [1024,128]
    float* out = (float*)d_out;                 // [8192,128]

    // Per-head buffers: [32 heads][2048 rows][128] elements each (16 MB bf16).
    const size_t HEADSZ = (size_t)32 * SEQ * HDIM;        // 8,388,608 elements

    short* XB    = (short*)d_ws;                          // 2 MB
    short* qkvT  = XB    + (size_t)MROWS * HDIM;
    short* projT = qkvT  + (size_t)QKVN * HDIM;
    short* Qh    = projT + (size_t)HDIM * YN;             // 16 MB
    short* Kh    = Qh    + HEADSZ;                        // 16 MB
    short* Vh    = Kh    + HEADSZ;                        // 16 MB
    short* Vtb   = Vh    + HEADSZ;                        // 16 MB
    short* Yb    = Vtb   + HEADSZ;                        // 16 MB  (~85 MB total)

    conv_x    <<<MROWS * HDIM / 1024, 256, 0, stream>>>(x, XB);
    conv_qkvT <<<QKVN * HDIM / 256,  256, 0, stream>>>(qkv, qkvT);
    conv_projT<<<HDIM * YN / 256,    256, 0, stream>>>(proj, projT);

    gemm_qkv<<<dim3(MROWS / 128, QKVN / 128), 256, 0, stream>>>(XB, qkvT, Qh, Kh, Vh);
    transp_v<<<dim3(SEQ / 64, HDIM / 64, 32), 256, 0, stream>>>(Vh, Vtb);
    attn7   <<<512, 256, 0, stream>>>(Qh, Kh, Vtb, Yb);
    gemm_out<<<MROWS / 16, 128, 0, stream>>>(Yb, projT, out);
}

// Round 11
// 174.508 us; speedup vs baseline: 2.4186x; 1.0666x over previous
//
#include <hip/hip_runtime.h>
#include <math.h>

// Problem constants
#define BATCH 4
#define SEQ   2048
#define HDIM  128
#define NHEAD 8
#define MROWS (BATCH*SEQ)    // 8192
#define QKVN  (3*NHEAD*HDIM) // 3072
#define YN    (NHEAD*HDIM)   // 1024

#define CS 0.12751744f   // (1/sqrt(128)) * log2(e)

using bfrag = __attribute__((ext_vector_type(8))) short;  // 8 bf16 (4 VGPRs)
using f32x4 = __attribute__((ext_vector_type(4))) float;
using s16x4 = __attribute__((ext_vector_type(4))) short;

__device__ __forceinline__ f32x4 mfma16(bfrag a, bfrag b, f32x4 c) {
    return __builtin_amdgcn_mfma_f32_16x16x32_bf16(a, b, c, 0, 0, 0);
}
__device__ __forceinline__ short f2bf(float f) {
    union { float f; unsigned u; } v; v.f = f;
    unsigned r = v.u + 0x7FFFu + ((v.u >> 16) & 1u);  // RNE
    return (short)(r >> 16);
}
__device__ __forceinline__ unsigned cvtpk(float lo, float hi) {
    unsigned r;
    asm("v_cvt_pk_bf16_f32 %0, %1, %2" : "=v"(r) : "v"(lo), "v"(hi));
    return r;   // bits[15:0]=bf16(lo), bits[31:16]=bf16(hi)
}
// swap halves between two registers: x.hi <-> y.lo
__device__ __forceinline__ void perm32swap(unsigned &x, unsigned &y) {
    asm volatile("v_permlane32_swap_b32 %0, %1" : "+v"(x), "+v"(y));
}
__device__ __forceinline__ f32x4 z4() { f32x4 z; z[0]=0.f; z[1]=0.f; z[2]=0.f; z[3]=0.f; return z; }

// ---------------------------------------------------------------------------
// Converters
// ---------------------------------------------------------------------------
__global__ __launch_bounds__(256) void conv_x(const float* __restrict__ x, short* __restrict__ XB) {
    int i = (blockIdx.x * 256 + threadIdx.x) * 4;
    float4 v = *(const float4*)(x + i);
    s16x4 o; o[0] = f2bf(v.x); o[1] = f2bf(v.y); o[2] = f2bf(v.z); o[3] = f2bf(v.w);
    *(s16x4*)(XB + i) = o;
}
__global__ __launch_bounds__(256) void conv_qkvT(const float* __restrict__ q, short* __restrict__ qT) {
    int t = blockIdx.x * 256 + threadIdx.x;         // 3072*128
    int n = t >> 7, k = t & 127;
    qT[t] = f2bf(q[(size_t)k * QKVN + n]);          // qT[n][k] = qkv[k][n]
}
__global__ __launch_bounds__(256) void conv_projT(const float* __restrict__ p, short* __restrict__ pT) {
    int t = blockIdx.x * 256 + threadIdx.x;         // 128*1024
    int h = t >> 10, r = t & 1023;
    pT[t] = f2bf(p[(size_t)r * HDIM + h]);          // pT[h][r] = proj[r][h]
}

// ---------------------------------------------------------------------------
// GEMM1: computes x @ qkv and scatters Q/K/V into per-head layouts:
//   Qh/Kh/Vh[(b*8+n)*2048 + s2][h]   (bf16, contiguous per head)
// ---------------------------------------------------------------------------
__global__ __launch_bounds__(256) void gemm_qkv(
    const short* __restrict__ XB, const short* __restrict__ qkvT,
    short* __restrict__ Qh, short* __restrict__ Kh, short* __restrict__ Vh)
{
    const int t = threadIdx.x, lane = t & 63, w = t >> 6;
    const int lr = lane & 15, lg = lane >> 4;
    const int m0 = blockIdx.x * 128 + (w >> 1) * 64;
    const int n0 = blockIdx.y * 128 + (w & 1) * 64;

    f32x4 acc[4][4];
    #pragma unroll
    for (int i = 0; i < 4; ++i)
        #pragma unroll
        for (int j = 0; j < 4; ++j) acc[i][j] = z4();

    #pragma unroll
    for (int c = 0; c < 4; ++c) {
        bfrag a[4], bb[4];
        #pragma unroll
        for (int rt = 0; rt < 4; ++rt)
            a[rt] = *(const bfrag*)(XB + (size_t)(m0 + rt * 16 + lr) * 128 + c * 32 + lg * 8);
        #pragma unroll
        for (int nt = 0; nt < 4; ++nt)
            bb[nt] = *(const bfrag*)(qkvT + (size_t)(n0 + nt * 16 + lr) * 128 + c * 32 + lg * 8);
        #pragma unroll
        for (int rt = 0; rt < 4; ++rt)
            #pragma unroll
            for (int nt = 0; nt < 4; ++nt)
                acc[rt][nt] = mfma16(a[rt], bb[nt], acc[rt][nt]);
    }

    const int part = blockIdx.y >> 3, c8 = blockIdx.y & 7;
    short* dst = (part == 0) ? Qh : ((part == 1) ? Kh : Vh);
    #pragma unroll
    for (int rt = 0; rt < 4; ++rt)
        #pragma unroll
        for (int j = 0; j < 4; ++j) {
            int r = m0 + rt * 16 + lg * 4 + j;
            int b = r >> 11, sl = r & 2047;
            int n = sl >> 8, s2 = (sl & 255) * 8 + c8;
            size_t rowbase = ((size_t)((b * 8 + n) * 2048 + s2)) * 128;
            #pragma unroll
            for (int nt = 0; nt < 4; ++nt) {
                int h = (w & 1) * 64 + nt * 16 + lr;
                dst[rowbase + h] = f2bf(acc[rt][nt][j]);
            }
        }
}

// ---------------------------------------------------------------------------
// Transpose V per head: Vh[bn][s2][d] -> Vt[bn][d][s2].
// ---------------------------------------------------------------------------
__global__ __launch_bounds__(256) void transp_v(
    const short* __restrict__ Vh, short* __restrict__ Vt)
{
    __shared__ short Ls[64][72];
    const int bn = blockIdx.z, s20 = blockIdx.x * 64, d0 = blockIdx.y * 64;
    const int t = threadIdx.x;
    const short* src = Vh + ((size_t)bn * SEQ + s20) * 128 + d0;
    {
        int r = t >> 2, ch = (t & 3) * 16;
        *(int4*)&Ls[r][ch]     = *(const int4*)(src + (size_t)r * 128 + ch);
        *(int4*)&Ls[r][ch + 8] = *(const int4*)(src + (size_t)r * 128 + ch + 8);
    }
    __syncthreads();
    {
        int dr = t >> 2, ch = (t & 3) * 16;
        short tmp[16];
        #pragma unroll
        for (int i = 0; i < 16; ++i) tmp[i] = Ls[ch + i][dr];
        short* dp = Vt + ((size_t)bn * HDIM + d0 + dr) * SEQ + s20 + ch;
        *(int4*)dp       = *(int4*)&tmp[0];
        *(int4*)(dp + 8) = *(int4*)&tmp[8];
    }
}

// ---------------------------------------------------------------------------
// attn8: attn7 skeleton with two structural fixes:
//  (1) P C-layout -> A-layout fully in-register: 8 cvt_pk + 4 permlane32_swap
//      + 8 shfl_xor(16) + selects. No Ps LDS, no per-step lgkmcnt(0) drains,
//      no conflicted Ps writes/reads (round-10's +9M conflict cycles).
//  (2) V single-buffered: V(s) issues at top of step s (after the barrier
//      freed Vls), completes under QK^T+softmax, counted vmcnt before PV
//      (T4). LDS 73->48 KB => 3 blocks/CU (was 2).
// K stays double-buffered (needed immediately at step top).
// ---------------------------------------------------------------------------
__global__ __launch_bounds__(256) void attn8(
    const short* __restrict__ Qh, const short* __restrict__ Kh,
    const short* __restrict__ Vt, short* __restrict__ Y)
{
    __shared__ __align__(16) short Kls[2][64 * 128];   // 32 KB (dbuf)
    __shared__ __align__(16) short Vls[128 * 64];      // 16 KB (single)

    const int t = threadIdx.x, lane = t & 63, w = t >> 6;
    const int lr = lane & 15, lg = lane >> 4;

    const int g  = blockIdx.x;        // 0..511
    const int bn = g & 31;            // head id; bn%8 == g%8 (XCD affinity)
    const int pp = g >> 5;            // pair id 0..15 -> tiles (pp, 31-pp)
    const int b  = bn >> 3, n = bn & 7;

    const short* Qb = Qh + (size_t)bn * SEQ * HDIM;
    const short* Kb = Kh + (size_t)bn * SEQ * HDIM;
    const short* Vb = Vt + (size_t)bn * HDIM * SEQ;

    // async staging: linear LDS dest, XOR-involution pre-swizzled global src
    auto stageK = [&](int buf, int k0) {
        #pragma unroll
        for (int i = 0; i < 4; ++i) {
            const int q = w * 4 + i;
            const int rowK = q * 4 + (lane >> 4);
            const short* src = Kb + (size_t)(k0 + rowK) * 128 + (((lane & 15) ^ (rowK & 7)) * 8);
            __builtin_amdgcn_global_load_lds(
                (const __attribute__((address_space(1))) unsigned int*)src,
                (__attribute__((address_space(3))) unsigned int*)&Kls[buf][q * 512 + lane * 8],
                16, 0, 0);
        }
    };
    auto stageV = [&](int k0) {
        #pragma unroll
        for (int i = 0; i < 4; ++i) {
            const int q = w * 4 + i;
            const int d = q * 8 + (lane >> 3);
            const short* src = Vb + (size_t)d * SEQ + k0 + (((lane & 7) ^ (d & 7)) * 8);
            __builtin_amdgcn_global_load_lds(
                (const __attribute__((address_space(1))) unsigned int*)src,
                (__attribute__((address_space(3))) unsigned int*)&Vls[q * 512 + lane * 8],
                16, 0, 0);
        }
    };

    const int sw = lr & 7;   // XOR involution key (row&7 for K rows and V rows)

    #pragma unroll 1
    for (int phase = 0; phase < 2; ++phase) {
        const int tile = phase ? pp : (31 - pp);    // long tile first
        const int q0 = tile * 64 + w * 16;

        bfrag qf[4];
        #pragma unroll
        for (int c = 0; c < 4; ++c)
            qf[c] = *(const bfrag*)(Qb + (size_t)(q0 + lr) * 128 + c * 32 + lg * 8);

        float mcs = -1.0e30f, l = 0.f;              // per-lane: q = q0 + lr
        f32x4 o[8];
        #pragma unroll
        for (int dt = 0; dt < 8; ++dt) o[dt] = z4();

        stageV(0);
        stageK(0, 0);
        __syncthreads();   // drains vmcnt -> K buf0 + V ready

        for (int s = 0; s <= tile; ++s) {
            const int cur = s & 1;
            const int k0 = s * 64;
            if (s > 0) stageV(k0);                   // Vls freed by prev barrier
            if (s < tile) stageK(cur ^ 1, k0 + 64);  // fill other K buffer

            // ---- swapped QK^T: sA[kt][j] = S^T[k = kt*16+lg*4+j][q = q0+lr]
            f32x4 sA[4];
            #pragma unroll
            for (int kt = 0; kt < 4; ++kt) sA[kt] = z4();
            const int ktend = (s == tile) ? (w + 1) : 4;  // skip fully-masked sub-tiles
            __builtin_amdgcn_s_setprio(1);
            for (int kt = 0; kt < ktend; ++kt) {
                const char* kbase = (const char*)&Kls[cur][0] + (kt * 16 + lr) * 256;
                #pragma unroll
                for (int c = 0; c < 4; ++c) {
                    bfrag kb = *(const bfrag*)(kbase + (((c * 4 + lg) ^ sw) * 16));
                    sA[kt] = mfma16(kb, qf[c], sA[kt]);   // swapped operands
                }
            }
            __builtin_amdgcn_s_setprio(0);

            // ---- causal mask (diagonal step only): k_local > q_local
            if (s == tile) {
                #pragma unroll
                for (int kt = 0; kt < 4; ++kt)
                    #pragma unroll
                    for (int j = 0; j < 4; ++j)
                        if (kt * 16 + lg * 4 + j > w * 16 + lr)
                            sA[kt][j] = -3.0e38f;
            }

            // ---- row max: in-lane tree + 2 cross-lg shuffles (full k-row)
            float mx = fmaxf(fmaxf(sA[0][0], sA[0][1]), fmaxf(sA[0][2], sA[0][3]));
            #pragma unroll
            for (int kt = 1; kt < 4; ++kt)
                mx = fmaxf(mx, fmaxf(fmaxf(sA[kt][0], sA[kt][1]),
                                     fmaxf(sA[kt][2], sA[kt][3])));
            mx = fmaxf(mx, __shfl_xor(mx, 16));
            mx = fmaxf(mx, __shfl_xor(mx, 32));
            const float pmx = mx * CS;

            // ---- T13 defer-rescale (rare)
            if (__any((pmx > mcs + 8.0f) ? 1 : 0)) {
                float nm = fmaxf(mcs, pmx);
                float al = exp2f(mcs - nm);
                mcs = nm;
                l *= al;
                float alj[4];
                #pragma unroll
                for (int j = 0; j < 4; ++j) alj[j] = __shfl(al, lg * 4 + j);
                #pragma unroll
                for (int dt = 0; dt < 8; ++dt)
                    #pragma unroll
                    for (int j = 0; j < 4; ++j) o[dt][j] *= alj[j];
            }

            // ---- P = exp2(S*CS - mcs) (lane-local row) + l-sum
            float p[4][4];
            float ls = 0.f;
            #pragma unroll
            for (int kt = 0; kt < 4; ++kt)
                #pragma unroll
                for (int j = 0; j < 4; ++j) {
                    p[kt][j] = exp2f(sA[kt][j] * CS - mcs);
                    ls += p[kt][j];
                }
            ls += __shfl_xor(ls, 16);
            ls += __shfl_xor(ls, 32);
            l += ls;

            // ---- in-register P redistribution (C-layout -> A-frag layout)
            // lane holds pairs pk[kt][0]=(k=16kt+4lg,+1), pk[kt][1]=(+2,+3).
            // pa0 needs k=8lg..8lg+7 (k<32); pa1 needs 32+8lg..+7.
            unsigned pk0[2], pk1[2], pk2[2], pk3[2];
            pk0[0] = cvtpk(p[0][0], p[0][1]); pk0[1] = cvtpk(p[0][2], p[0][3]);
            pk1[0] = cvtpk(p[1][0], p[1][1]); pk1[1] = cvtpk(p[1][2], p[1][3]);
            pk2[0] = cvtpk(p[2][0], p[2][1]); pk2[1] = cvtpk(p[2][2], p[2][3]);
            pk3[0] = cvtpk(p[3][0], p[3][1]); pk3[1] = cvtpk(p[3][2], p[3][3]);

            const bool hi16 = (lg & 1);
            uint4 w0, w1;
            {   // pa0 from (kt0, kt1)
                unsigned A = pk0[0], C = pk1[0];
                perm32swap(A, C);                         // A={a.lo,c.lo} C={a.hi,c.hi}
                unsigned A16 = __shfl_xor((int)A, 16), C16 = __shfl_xor((int)C, 16);
                w0.x = hi16 ? C16 : A;
                w0.z = hi16 ? C   : A16;
                unsigned B = pk0[1], D = pk1[1];
                perm32swap(B, D);
                unsigned B16 = __shfl_xor((int)B, 16), D16 = __shfl_xor((int)D, 16);
                w0.y = hi16 ? D16 : B;
                w0.w = hi16 ? D   : B16;
            }
            {   // pa1 from (kt2, kt3)
                unsigned E = pk2[0], G = pk3[0];
                perm32swap(E, G);
                unsigned E16 = __shfl_xor((int)E, 16), G16 = __shfl_xor((int)G, 16);
                w1.x = hi16 ? G16 : E;
                w1.z = hi16 ? G   : E16;
                unsigned F = pk2[1], H = pk3[1];
                perm32swap(F, H);
                unsigned F16 = __shfl_xor((int)F, 16), H16 = __shfl_xor((int)H, 16);
                w1.y = hi16 ? H16 : F;
                w1.w = hi16 ? H   : F16;
            }
            union { uint4 u; bfrag f; } cv0, cv1;
            cv0.u = w0; cv1.u = w1;
            bfrag pa0 = cv0.f, pa1 = cv1.f;

            // ---- wait for this step's V loads (K(s+1) may stay in flight)
            if (s > 0) {
                if (s < tile) asm volatile("s_waitcnt vmcnt(4)" ::: "memory");
                else          asm volatile("s_waitcnt vmcnt(0)" ::: "memory");
            }

            // ---- PV from swizzled Vls
            __builtin_amdgcn_s_setprio(1);
            #pragma unroll
            for (int dt = 0; dt < 8; ++dt) {
                const char* vbase = (const char*)&Vls[0] + (dt * 16 + lr) * 128;
                bfrag vb0 = *(const bfrag*)(vbase + ((lg ^ sw) * 16));
                bfrag vb1 = *(const bfrag*)(vbase + (((4 + lg) ^ sw) * 16));
                o[dt] = mfma16(pa0, vb0, o[dt]);
                o[dt] = mfma16(pa1, vb1, o[dt]);
            }
            __builtin_amdgcn_s_setprio(0);

            __syncthreads();   // drains K(s+1) loads; frees Vls for next step
        }

        // ---- epilogue: l (q=lr layout) -> per-j inverses, scatter bf16 to Y
        float inv[4];
        #pragma unroll
        for (int j = 0; j < 4; ++j) inv[j] = 1.0f / __shfl(l, lg * 4 + j);
        #pragma unroll
        for (int j = 0; j < 4; ++j) {
            int s2 = q0 + lg * 4 + j;
            size_t yrow = (size_t)b * SEQ + n * 256 + (s2 >> 3);
            short* yp = Y + yrow * YN + (s2 & 7) * 128 + lr;
            #pragma unroll
            for (int dt = 0; dt < 8; ++dt)
                yp[dt * 16] = f2bf(o[dt][j] * inv[j]);
        }
    }
}

// ---------------------------------------------------------------------------
// GEMM2: out[8192][128] (f32) = Yb[8192][1024](bf16) @ proj, B as projT[h][k].
// ---------------------------------------------------------------------------
__global__ __launch_bounds__(128) void gemm_out(
    const short* __restrict__ Yb, const short* __restrict__ projT, float* __restrict__ out)
{
    const int t = threadIdx.x, lane = t & 63, w = t >> 6;   // w in 0..1
    const int lr = lane & 15, lg = lane >> 4;
    const int m0 = blockIdx.x * 16;
    const int n0 = w * 64;

    f32x4 acc[4];
    #pragma unroll
    for (int j = 0; j < 4; ++j) acc[j] = z4();

    for (int c = 0; c < 32; ++c) {
        bfrag a = *(const bfrag*)(Yb + (size_t)(m0 + lr) * YN + c * 32 + lg * 8);
        #pragma unroll
        for (int nt = 0; nt < 4; ++nt) {
            bfrag bb = *(const bfrag*)(projT + (size_t)(n0 + nt * 16 + lr) * YN + c * 32 + lg * 8);
            acc[nt] = mfma16(a, bb, acc[nt]);
        }
    }
    #pragma unroll
    for (int nt = 0; nt < 4; ++nt)
        #pragma unroll
        for (int j = 0; j < 4; ++j)
            out[(size_t)(m0 + lg * 4 + j) * HDIM + n0 + nt * 16 + lr] = acc[nt][j];
}

// ---------------------------------------------------------------------------
extern "C" void kernel_launch(void* const* d_in, const int* in_sizes, int n_in,
                              void* d_out, int out_size, void* d_ws, size_t ws_size,
                              hipStream_t stream)
{
    const float* x    = (const float*)d_in[0];  // [4,2048,128]
    const float* qkv  = (const float*)d_in[1];  // [128,3072]
    const float* proj = (const float*)d_in[2];  // [1024,128]
    float* out = (float*)d_out;                 // [8192,128]

    // Per-head buffers: [32 heads][2048 rows][128] elements each (16 MB bf16).
    const size_t HEADSZ = (size_t)32 * SEQ * HDIM;        // 8,388,608 elements

    short* XB    = (short*)d_ws;                          // 2 MB
    short* qkvT  = XB    + (size_t)MROWS * HDIM;
    short* projT = qkvT  + (size_t)QKVN * HDIM;
    short* Qh    = projT + (size_t)HDIM * YN;             // 16 MB
    short* Kh    = Qh    + HEADSZ;                        // 16 MB
    short* Vh    = Kh    + HEADSZ;                        // 16 MB
    short* Vtb   = Vh    + HEADSZ;                        // 16 MB
    short* Yb    = Vtb   + HEADSZ;                        // 16 MB  (~85 MB total)

    conv_x    <<<MROWS * HDIM / 1024, 256, 0, stream>>>(x, XB);
    conv_qkvT <<<QKVN * HDIM / 256,  256, 0, stream>>>(qkv, qkvT);
    conv_projT<<<HDIM * YN / 256,    256, 0, stream>>>(proj, projT);

    gemm_qkv<<<dim3(MROWS / 128, QKVN / 128), 256, 0, stream>>>(XB, qkvT, Qh, Kh, Vh);
    transp_v<<<dim3(SEQ / 64, HDIM / 64, 32), 256, 0, stream>>>(Vh, Vtb);
    attn8   <<<512, 256, 0, stream>>>(Qh, Kh, Vtb, Yb);
    gemm_out<<<MROWS / 16, 128, 0, stream>>>(Yb, projT, out);
}